// Round 2
// baseline (1509.417 us; speedup 1.0000x reference)
//
#include <hip/hip_runtime.h>
#include <hip/hip_bf16.h>
#include <math.h>

typedef __attribute__((ext_vector_type(4))) float f32x4;
typedef __attribute__((ext_vector_type(8))) short bf16x8;

__device__ __forceinline__ unsigned short f2bf(float f) {
  unsigned int x = __builtin_bit_cast(unsigned int, f);
  x += 0x7fffu + ((x >> 16) & 1u);
  return (unsigned short)(x >> 16);
}

__device__ __forceinline__ void gload_lds16(const void* g, void* l) {
  __builtin_amdgcn_global_load_lds(
      (const __attribute__((address_space(1))) unsigned int*)g,
      (__attribute__((address_space(3))) unsigned int*)l, 16, 0, 0);
}

// ---------------- f32 -> bf16 cast ----------------
__global__ void cvt_f32_bf16(const float* __restrict__ s, unsigned short* __restrict__ d, int n) {
  int i = blockIdx.x * 256 + threadIdx.x;
  if (i < n) d[i] = f2bf(s[i]);
}

// ---------------- LayerNorm (optionally with shift+window gather) ----------------
template <int REMAP>
__global__ __launch_bounds__(256)
void ln_kernel(const float* __restrict__ x, const float* __restrict__ g,
               const float* __restrict__ b, unsigned short* __restrict__ dst_o) {
  int r = blockIdx.x * 4 + (threadIdx.x >> 6);
  int lane = threadIdx.x & 63;
  size_t src;
  if (REMAP) {
    int w = r >> 6, t = r & 63;
    int bb = w >> 8, wi = (w >> 4) & 15, wj = w & 15;
    int i = t >> 3, j = t & 7;
    int p = (wi * 8 + i + 4) & 127, q = (wj * 8 + j + 4) & 127;
    src = ((size_t)bb * 16384 + p * 128 + q) * 384;
  } else {
    src = (size_t)r * 384;
  }
  float v[6];
  float s = 0.f, s2 = 0.f;
#pragma unroll
  for (int m = 0; m < 6; ++m) {
    v[m] = x[src + lane + 64 * m];
    s += v[m];
    s2 += v[m] * v[m];
  }
#pragma unroll
  for (int o2 = 1; o2 < 64; o2 <<= 1) {
    s += __shfl_xor(s, o2);
    s2 += __shfl_xor(s2, o2);
  }
  float mu = s * (1.f / 384.f);
  float var = s2 * (1.f / 384.f) - mu * mu;
  float ri = rsqrtf(var + 1e-5f);
  size_t dst = (size_t)r * 384;
#pragma unroll
  for (int m = 0; m < 6; ++m) {
    int c = lane + 64 * m;
    dst_o[dst + c] = f2bf((v[m] - mu) * ri * g[c] + b[c]);
  }
}

// ---------------- GEMM: C(M,N) = A(M,K) * B(N,K)^T ----------------
// A staged in LDS (double-buffered, 2-phase); B fragments read directly from
// global (weights are <=1.2MB, L2-resident). One __syncthreads per K-step.
// EPI 0: out = bf16(acc + bias)                       -> Obf
// EPI 1: out = bf16(gelu(acc + bias))                 -> Obf
// EPI 2: proj: scatter window->image, += resid(x)     -> Of (f32)
// EPI 3: out = acc + bias + resid                     -> Of (f32)
template <int EPI>
__global__ __launch_bounds__(256, 4)
void gemm_bt(const unsigned short* __restrict__ A, const unsigned short* __restrict__ Bw,
             const float* __restrict__ bias, int M, int N, int K, int NT,
             unsigned short* __restrict__ Obf, const float* __restrict__ resid,
             float* __restrict__ Of) {
  __shared__ unsigned short smA[2][128 * 64];
  const int tid = threadIdx.x;
  const int lane = tid & 63;
  const int wid = tid >> 6;
  const int wm = wid >> 1, wn = wid & 1;
  const int li = lane & 15, lg = lane >> 4;

  // bijective XCD swizzle (m204): each XCD gets a contiguous band of m-panels
  const int nwg = gridDim.x;
  const int orig = blockIdx.x;
  const int q = nwg >> 3, r = nwg & 7;
  const int xcd = orig & 7, loc = orig >> 3;
  const int wg = (xcd < r ? xcd * (q + 1) : r * (q + 1) + (xcd - r) * q) + loc;
  const int m0 = (wg / NT) * 128;
  const int n0 = (wg % NT) * 128;

  const int srow = wid * 32 + (lane >> 3);  // staging row for this lane
  const int scol = (lane & 7) * 8;          // staging col (16B per lane)
  const unsigned short* gA = A + (size_t)(m0 + srow) * K + scol;
  const unsigned short* gB[4];
#pragma unroll
  for (int nf = 0; nf < 4; ++nf)
    gB[nf] = Bw + (size_t)(n0 + wn * 64 + nf * 16 + li) * K + lg * 8;

  f32x4 acc[4][4] = {};
  const int nk = K >> 6;

  // prologue: stage K-step 0 into buffer 0
#pragma unroll
  for (int c = 0; c < 4; ++c)
    gload_lds16(gA + (size_t)(c * 8) * K, &smA[0][(wid * 32 + c * 8) * 64]);
  __syncthreads();

  for (int k0 = 0; k0 < nk; ++k0) {
    const int cur = k0 & 1;
    if (k0 + 1 < nk) {  // issue next-step stage early; latency hides under compute
#pragma unroll
      for (int c = 0; c < 4; ++c)
        gload_lds16(gA + (size_t)(c * 8) * K + (k0 + 1) * 64,
                    &smA[cur ^ 1][(wid * 32 + c * 8) * 64]);
    }
#pragma unroll
    for (int kk = 0; kk < 2; ++kk) {
      bf16x8 a[4], bb[4];
#pragma unroll
      for (int f = 0; f < 4; ++f)
        a[f] = *(const bf16x8*)&smA[cur][(wm * 64 + f * 16 + li) * 64 + kk * 32 + lg * 8];
#pragma unroll
      for (int f = 0; f < 4; ++f)
        bb[f] = *(const bf16x8*)&gB[f][(size_t)(k0 * 64 + kk * 32)];
#pragma unroll
      for (int mf = 0; mf < 4; ++mf)
#pragma unroll
        for (int nf = 0; nf < 4; ++nf)
          acc[mf][nf] = __builtin_amdgcn_mfma_f32_16x16x32_bf16(a[mf], bb[nf], acc[mf][nf], 0, 0, 0);
    }
    __syncthreads();  // drains vmcnt: the stage issued above had full compute phase to land
  }

  // epilogue: C/D layout col = lane&15, row = (lane>>4)*4 + reg
#pragma unroll
  for (int mf = 0; mf < 4; ++mf) {
#pragma unroll
    for (int r2 = 0; r2 < 4; ++r2) {
      int mrow = m0 + wm * 64 + mf * 16 + lg * 4 + r2;
      size_t orow = (size_t)mrow;
      if (EPI == 2) {
        int w = mrow >> 6, t = mrow & 63;
        int bb2 = w >> 8, wi = (w >> 4) & 15, wj = w & 15;
        int i = t >> 3, j = t & 7;
        int p = (wi * 8 + i + 4) & 127, qq = (wj * 8 + j + 4) & 127;
        orow = (size_t)bb2 * 16384 + p * 128 + qq;
      }
#pragma unroll
      for (int nf = 0; nf < 4; ++nf) {
        int col = n0 + wn * 64 + nf * 16 + li;
        float v = acc[mf][nf][r2] + bias[col];
        if (EPI == 0) {
          Obf[(size_t)mrow * N + col] = f2bf(v);
        } else if (EPI == 1) {
          float gl = 0.5f * v * (1.f + erff(v * 0.70710678118654752f));
          Obf[(size_t)mrow * N + col] = f2bf(gl);
        } else if (EPI == 2) {
          Of[orow * 384 + col] = v + resid[orow * 384 + col];
        } else {
          Of[(size_t)mrow * N + col] = v + resid[(size_t)mrow * N + col];
        }
      }
    }
  }
}

// ---------------- windowed attention: one block per window, 4 waves x 3 heads ----------------
__global__ __launch_bounds__(256, 2)
void attn_kernel(const unsigned short* __restrict__ qkv, const float* __restrict__ btab,
                 const float* __restrict__ mask, unsigned short* __restrict__ out) {
  __shared__ unsigned short v_lds[4][64 * 40];  // V tile, row stride 40
  __shared__ unsigned short p_lds[4][64 * 72];  // P tile, row stride 72
  const int w = blockIdx.x;
  const int tid = threadIdx.x;
  const int wid = tid >> 6, lane = tid & 63;
  const int li = lane & 15, lg = lane >> 4;
  const float* mrow = mask + (size_t)(w & 255) * 4096;
  const size_t base = (size_t)w * 64;
  const float SC = 0.17677669529663688f;  // 32^-0.5

#pragma unroll 1
  for (int hi = 0; hi < 3; ++hi) {
    int h = wid * 3 + hi;
    bf16x8 aq[4], bk[4];
#pragma unroll
    for (int f = 0; f < 4; ++f) {
      size_t off = (base + f * 16 + li) * 1152 + h * 32 + lg * 8;
      aq[f] = *(const bf16x8*)&qkv[off];
      bk[f] = *(const bf16x8*)&qkv[off + 384];
    }
    f32x4 s[4][4] = {};
#pragma unroll
    for (int mf = 0; mf < 4; ++mf)
#pragma unroll
      for (int nf = 0; nf < 4; ++nf)
        s[mf][nf] = __builtin_amdgcn_mfma_f32_16x16x32_bf16(aq[mf], bk[nf], s[mf][nf], 0, 0, 0);

    {
      const unsigned short* vp = &qkv[(base + lane) * 1152 + 768 + h * 32];
      unsigned short* dp = &v_lds[wid][lane * 40];
#pragma unroll
      for (int c = 0; c < 4; ++c) *(bf16x8*)&dp[c * 8] = *(const bf16x8*)&vp[c * 8];
    }

#pragma unroll
    for (int mf = 0; mf < 4; ++mf) {
#pragma unroll
      for (int r = 0; r < 4; ++r) {
        int m = mf * 16 + lg * 4 + r;
        float mx = -1e30f;
#pragma unroll
        for (int nf = 0; nf < 4; ++nf) {
          int n = nf * 16 + li;
          int ridx = ((m >> 3) - (n >> 3) + 7) * 15 + (m & 7) - (n & 7) + 7;
          float val = s[mf][nf][r] * SC + btab[ridx * 12 + h] + mrow[m * 64 + n];
          s[mf][nf][r] = val;
          mx = fmaxf(mx, val);
        }
#pragma unroll
        for (int o2 = 1; o2 < 16; o2 <<= 1) mx = fmaxf(mx, __shfl_xor(mx, o2));
        float sum = 0.f;
#pragma unroll
        for (int nf = 0; nf < 4; ++nf) {
          float e = __expf(s[mf][nf][r] - mx);
          s[mf][nf][r] = e;
          sum += e;
        }
#pragma unroll
        for (int o2 = 1; o2 < 16; o2 <<= 1) sum += __shfl_xor(sum, o2);
        float inv = 1.f / sum;
#pragma unroll
        for (int nf = 0; nf < 4; ++nf) s[mf][nf][r] *= inv;
      }
    }

#pragma unroll
    for (int mf = 0; mf < 4; ++mf)
#pragma unroll
      for (int nf = 0; nf < 4; ++nf)
#pragma unroll
        for (int r = 0; r < 4; ++r) {
          int m = mf * 16 + lg * 4 + r, n = nf * 16 + li;
          p_lds[wid][m * 72 + n] = f2bf(s[mf][nf][r]);
        }

    f32x4 o[4][2] = {};
#pragma unroll
    for (int kf = 0; kf < 2; ++kf) {
      bf16x8 bv[2];
#pragma unroll
      for (int df = 0; df < 2; ++df) {
        bf16x8 t;
#pragma unroll
        for (int e = 0; e < 8; ++e)
          t[e] = (short)v_lds[wid][(kf * 32 + lg * 8 + e) * 40 + df * 16 + li];
        bv[df] = t;
      }
#pragma unroll
      for (int mf = 0; mf < 4; ++mf) {
        bf16x8 pa = *(const bf16x8*)&p_lds[wid][(mf * 16 + li) * 72 + kf * 32 + lg * 8];
#pragma unroll
        for (int df = 0; df < 2; ++df)
          o[mf][df] = __builtin_amdgcn_mfma_f32_16x16x32_bf16(pa, bv[df], o[mf][df], 0, 0, 0);
      }
    }

#pragma unroll
    for (int mf = 0; mf < 4; ++mf)
#pragma unroll
      for (int df = 0; df < 2; ++df)
#pragma unroll
        for (int r = 0; r < 4; ++r) {
          size_t row = base + mf * 16 + lg * 4 + r;
          out[row * 384 + h * 32 + df * 16 + li] = f2bf(o[mf][df][r]);
        }
  }
}

extern "C" void kernel_launch(void* const* d_in, const int* in_sizes, int n_in,
                              void* d_out, int out_size, void* d_ws, size_t ws_size,
                              hipStream_t stream) {
  const float* x      = (const float*)d_in[0];
  const float* qkv_w  = (const float*)d_in[1];
  const float* qkv_b  = (const float*)d_in[2];
  const float* proj_w = (const float*)d_in[3];
  const float* proj_b = (const float*)d_in[4];
  const float* rel    = (const float*)d_in[5];
  const float* g1     = (const float*)d_in[6];
  const float* b1     = (const float*)d_in[7];
  const float* g2     = (const float*)d_in[8];
  const float* b2     = (const float*)d_in[9];
  const float* fc1_w  = (const float*)d_in[10];
  const float* fc1_b  = (const float*)d_in[11];
  const float* fc2_w  = (const float*)d_in[12];
  const float* fc2_b  = (const float*)d_in[13];
  const float* mask   = (const float*)d_in[14];
  float* out = (float*)d_out;
  char* ws = (char*)d_ws;

  const int M = 131072;  // B * H * W tokens
  unsigned short* hw     = (unsigned short*)ws;
  unsigned short* qkv    = (unsigned short*)(ws + 100663296);
  unsigned short* hmid   = (unsigned short*)ws;
  unsigned short* attn_o = (unsigned short*)(ws + 402653184);
  unsigned short* ln2o   = attn_o;
  float*          x1     = (float*)(ws + 503316480);
  unsigned short* wq     = (unsigned short*)(ws + 704643072);
  unsigned short* wp     = wq + 442368;
  unsigned short* w1     = wp + 147456;
  unsigned short* w2     = w1 + 589824;

  cvt_f32_bf16<<<(442368 + 255) / 256, 256, 0, stream>>>(qkv_w, wq, 442368);
  cvt_f32_bf16<<<(147456 + 255) / 256, 256, 0, stream>>>(proj_w, wp, 147456);
  cvt_f32_bf16<<<(589824 + 255) / 256, 256, 0, stream>>>(fc1_w, w1, 589824);
  cvt_f32_bf16<<<(589824 + 255) / 256, 256, 0, stream>>>(fc2_w, w2, 589824);

  // LN1 + shift + window partition
  ln_kernel<1><<<M / 4, 256, 0, stream>>>(x, g1, b1, hw);

  // QKV projection (grid linearized: wg = mtile*NT + ntile)
  gemm_bt<0><<<9 * 1024, 256, 0, stream>>>(hw, wq, qkv_b, M, 1152, 384, 9, qkv, nullptr, nullptr);

  // windowed attention
  attn_kernel<<<2048, 256, 0, stream>>>(qkv, rel, mask, attn_o);

  // proj + window reverse + unshift + residual -> x1
  gemm_bt<2><<<3 * 1024, 256, 0, stream>>>(attn_o, wp, proj_b, M, 384, 384, 3, nullptr, x, x1);

  // LN2
  ln_kernel<0><<<M / 4, 256, 0, stream>>>(x1, g2, b2, ln2o);

  // FC1 + GELU
  gemm_bt<1><<<12 * 1024, 256, 0, stream>>>(ln2o, w1, fc1_b, M, 1536, 384, 12, hmid, nullptr, nullptr);

  // FC2 + residual -> out
  gemm_bt<3><<<3 * 1024, 256, 0, stream>>>(hmid, w2, fc2_b, M, 384, 1536, 3, nullptr, x1, out);
}

// Round 3
// 1280.325 us; speedup vs baseline: 1.1789x; 1.1789x over previous
//
#include <hip/hip_runtime.h>
#include <hip/hip_bf16.h>
#include <math.h>

typedef __attribute__((ext_vector_type(4))) float f32x4;
typedef __attribute__((ext_vector_type(8))) short bf16x8;

__device__ __forceinline__ unsigned short f2bf(float f) {
  unsigned int x = __builtin_bit_cast(unsigned int, f);
  x += 0x7fffu + ((x >> 16) & 1u);
  return (unsigned short)(x >> 16);
}

__device__ __forceinline__ void gload_lds16(const void* g, void* l) {
  __builtin_amdgcn_global_load_lds(
      (const __attribute__((address_space(1))) unsigned int*)g,
      (__attribute__((address_space(3))) unsigned int*)l, 16, 0, 0);
}

// ---------------- f32 -> bf16 cast ----------------
__global__ void cvt_f32_bf16(const float* __restrict__ s, unsigned short* __restrict__ d, int n) {
  int i = blockIdx.x * 256 + threadIdx.x;
  if (i < n) d[i] = f2bf(s[i]);
}

// ---------------- LayerNorm (optionally with shift+window gather) ----------------
template <int REMAP>
__global__ __launch_bounds__(256)
void ln_kernel(const float* __restrict__ x, const float* __restrict__ g,
               const float* __restrict__ b, unsigned short* __restrict__ dst_o) {
  int r = blockIdx.x * 4 + (threadIdx.x >> 6);
  int lane = threadIdx.x & 63;
  size_t src;
  if (REMAP) {
    int w = r >> 6, t = r & 63;
    int bb = w >> 8, wi = (w >> 4) & 15, wj = w & 15;
    int i = t >> 3, j = t & 7;
    int p = (wi * 8 + i + 4) & 127, q = (wj * 8 + j + 4) & 127;
    src = ((size_t)bb * 16384 + p * 128 + q) * 384;
  } else {
    src = (size_t)r * 384;
  }
  float v[6];
  float s = 0.f, s2 = 0.f;
#pragma unroll
  for (int m = 0; m < 6; ++m) {
    v[m] = x[src + lane + 64 * m];
    s += v[m];
    s2 += v[m] * v[m];
  }
#pragma unroll
  for (int o2 = 1; o2 < 64; o2 <<= 1) {
    s += __shfl_xor(s, o2);
    s2 += __shfl_xor(s2, o2);
  }
  float mu = s * (1.f / 384.f);
  float var = s2 * (1.f / 384.f) - mu * mu;
  float ri = rsqrtf(var + 1e-5f);
  size_t dst = (size_t)r * 384;
#pragma unroll
  for (int m = 0; m < 6; ++m) {
    int c = lane + 64 * m;
    dst_o[dst + c] = f2bf((v[m] - mu) * ri * g[c] + b[c]);
  }
}

// ---------------- GEMM: C(M,N) = A(M,K) * B(N,K)^T ----------------
// A and B staged via global_load_lds into double-buffered LDS; 2-phase
// schedule: stage K-step k+1, compute k, one __syncthreads per step
// (compiler's vmcnt(0)-before-barrier drains loads that had the whole
// compute phase in flight). Linearized grid + bijective XCD swizzle.
// EPI 0: out = bf16(acc + bias)                       -> Obf
// EPI 1: out = bf16(gelu(acc + bias))                 -> Obf
// EPI 2: proj: scatter window->image, += resid(x)     -> Of (f32)
// EPI 3: out = acc + bias + resid                     -> Of (f32)
template <int EPI>
__global__ __launch_bounds__(256, 2)
void gemm_bt(const unsigned short* __restrict__ A, const unsigned short* __restrict__ Bw,
             const float* __restrict__ bias, int M, int N, int K, int NT,
             unsigned short* __restrict__ Obf, const float* __restrict__ resid,
             float* __restrict__ Of) {
  __shared__ unsigned short smA[2][128 * 64];
  __shared__ unsigned short smB[2][128 * 64];
  const int tid = threadIdx.x;
  const int lane = tid & 63;
  const int wid = tid >> 6;
  const int wm = wid >> 1, wn = wid & 1;
  const int li = lane & 15, lg = lane >> 4;

  // bijective XCD swizzle (m204): each XCD owns a contiguous band of wg ->
  // consecutive m-panels stay on one XCD's L2 (round-2: FETCH 399->60 MB)
  const int nwg = gridDim.x;
  const int orig = blockIdx.x;
  const int q = nwg >> 3, r = nwg & 7;
  const int xcd = orig & 7, loc = orig >> 3;
  const int wg = (xcd < r ? xcd * (q + 1) : r * (q + 1) + (xcd - r) * q) + loc;
  const int m0 = (wg / NT) * 128;
  const int n0 = (wg % NT) * 128;

  const int srow = wid * 32 + (lane >> 3);  // staging row for this lane
  const int scol = (lane & 7) * 8;          // staging col (16B per lane)
  const unsigned short* gA = A + (size_t)(m0 + srow) * K + scol;
  const unsigned short* gB = Bw + (size_t)(n0 + srow) * K + scol;

  f32x4 acc[4][4] = {};
  const int nk = K >> 6;

  // prologue: stage K-step 0 into buffer 0
#pragma unroll
  for (int c = 0; c < 4; ++c) {
    gload_lds16(gA + (size_t)(c * 8) * K, &smA[0][(wid * 32 + c * 8) * 64]);
    gload_lds16(gB + (size_t)(c * 8) * K, &smB[0][(wid * 32 + c * 8) * 64]);
  }
  __syncthreads();

  for (int k0 = 0; k0 < nk; ++k0) {
    const int cur = k0 & 1;
    if (k0 + 1 < nk) {  // issue next-step stage early; latency hides under MFMA
#pragma unroll
      for (int c = 0; c < 4; ++c) {
        gload_lds16(gA + (size_t)(c * 8) * K + (k0 + 1) * 64,
                    &smA[cur ^ 1][(wid * 32 + c * 8) * 64]);
        gload_lds16(gB + (size_t)(c * 8) * K + (k0 + 1) * 64,
                    &smB[cur ^ 1][(wid * 32 + c * 8) * 64]);
      }
    }
#pragma unroll
    for (int kk = 0; kk < 2; ++kk) {
      bf16x8 a[4], bb[4];
#pragma unroll
      for (int f = 0; f < 4; ++f) {
        a[f] = *(const bf16x8*)&smA[cur][(wm * 64 + f * 16 + li) * 64 + kk * 32 + lg * 8];
        bb[f] = *(const bf16x8*)&smB[cur][(wn * 64 + f * 16 + li) * 64 + kk * 32 + lg * 8];
      }
#pragma unroll
      for (int mf = 0; mf < 4; ++mf)
#pragma unroll
        for (int nf = 0; nf < 4; ++nf)
          acc[mf][nf] = __builtin_amdgcn_mfma_f32_16x16x32_bf16(a[mf], bb[nf], acc[mf][nf], 0, 0, 0);
    }
    __syncthreads();  // drains this wave's stage loads; they had full compute to land
  }

  // epilogue: C/D layout col = lane&15, row = (lane>>4)*4 + reg
#pragma unroll
  for (int mf = 0; mf < 4; ++mf) {
#pragma unroll
    for (int r2 = 0; r2 < 4; ++r2) {
      int mrow = m0 + wm * 64 + mf * 16 + lg * 4 + r2;
      size_t orow = (size_t)mrow;
      if (EPI == 2) {
        int w = mrow >> 6, t = mrow & 63;
        int bb2 = w >> 8, wi = (w >> 4) & 15, wj = w & 15;
        int i = t >> 3, j = t & 7;
        int p = (wi * 8 + i + 4) & 127, qq = (wj * 8 + j + 4) & 127;
        orow = (size_t)bb2 * 16384 + p * 128 + qq;
      }
#pragma unroll
      for (int nf = 0; nf < 4; ++nf) {
        int col = n0 + wn * 64 + nf * 16 + li;
        float v = acc[mf][nf][r2] + bias[col];
        if (EPI == 0) {
          Obf[(size_t)mrow * N + col] = f2bf(v);
        } else if (EPI == 1) {
          float gl = 0.5f * v * (1.f + erff(v * 0.70710678118654752f));
          Obf[(size_t)mrow * N + col] = f2bf(gl);
        } else if (EPI == 2) {
          Of[orow * 384 + col] = v + resid[orow * 384 + col];
        } else {
          Of[(size_t)mrow * N + col] = v + resid[(size_t)mrow * N + col];
        }
      }
    }
  }
}

// ---------------- windowed attention: one block per window, 4 waves x 3 heads ----------------
__global__ __launch_bounds__(256, 2)
void attn_kernel(const unsigned short* __restrict__ qkv, const float* __restrict__ btab,
                 const float* __restrict__ mask, unsigned short* __restrict__ out) {
  __shared__ unsigned short v_lds[4][64 * 40];  // V tile, row stride 40
  __shared__ unsigned short p_lds[4][64 * 72];  // P tile, row stride 72
  const int w = blockIdx.x;
  const int tid = threadIdx.x;
  const int wid = tid >> 6, lane = tid & 63;
  const int li = lane & 15, lg = lane >> 4;
  const float* mrow = mask + (size_t)(w & 255) * 4096;
  const size_t base = (size_t)w * 64;
  const float SC = 0.17677669529663688f;  // 32^-0.5

#pragma unroll 1
  for (int hi = 0; hi < 3; ++hi) {
    int h = wid * 3 + hi;
    bf16x8 aq[4], bk[4];
#pragma unroll
    for (int f = 0; f < 4; ++f) {
      size_t off = (base + f * 16 + li) * 1152 + h * 32 + lg * 8;
      aq[f] = *(const bf16x8*)&qkv[off];
      bk[f] = *(const bf16x8*)&qkv[off + 384];
    }
    f32x4 s[4][4] = {};
#pragma unroll
    for (int mf = 0; mf < 4; ++mf)
#pragma unroll
      for (int nf = 0; nf < 4; ++nf)
        s[mf][nf] = __builtin_amdgcn_mfma_f32_16x16x32_bf16(aq[mf], bk[nf], s[mf][nf], 0, 0, 0);

    {
      const unsigned short* vp = &qkv[(base + lane) * 1152 + 768 + h * 32];
      unsigned short* dp = &v_lds[wid][lane * 40];
#pragma unroll
      for (int c = 0; c < 4; ++c) *(bf16x8*)&dp[c * 8] = *(const bf16x8*)&vp[c * 8];
    }

#pragma unroll
    for (int mf = 0; mf < 4; ++mf) {
#pragma unroll
      for (int r = 0; r < 4; ++r) {
        int m = mf * 16 + lg * 4 + r;
        float mx = -1e30f;
#pragma unroll
        for (int nf = 0; nf < 4; ++nf) {
          int n = nf * 16 + li;
          int ridx = ((m >> 3) - (n >> 3) + 7) * 15 + (m & 7) - (n & 7) + 7;
          float val = s[mf][nf][r] * SC + btab[ridx * 12 + h] + mrow[m * 64 + n];
          s[mf][nf][r] = val;
          mx = fmaxf(mx, val);
        }
#pragma unroll
        for (int o2 = 1; o2 < 16; o2 <<= 1) mx = fmaxf(mx, __shfl_xor(mx, o2));
        float sum = 0.f;
#pragma unroll
        for (int nf = 0; nf < 4; ++nf) {
          float e = __expf(s[mf][nf][r] - mx);
          s[mf][nf][r] = e;
          sum += e;
        }
#pragma unroll
        for (int o2 = 1; o2 < 16; o2 <<= 1) sum += __shfl_xor(sum, o2);
        float inv = 1.f / sum;
#pragma unroll
        for (int nf = 0; nf < 4; ++nf) s[mf][nf][r] *= inv;
      }
    }

#pragma unroll
    for (int mf = 0; mf < 4; ++mf)
#pragma unroll
      for (int nf = 0; nf < 4; ++nf)
#pragma unroll
        for (int r = 0; r < 4; ++r) {
          int m = mf * 16 + lg * 4 + r, n = nf * 16 + li;
          p_lds[wid][m * 72 + n] = f2bf(s[mf][nf][r]);
        }

    f32x4 o[4][2] = {};
#pragma unroll
    for (int kf = 0; kf < 2; ++kf) {
      bf16x8 bv[2];
#pragma unroll
      for (int df = 0; df < 2; ++df) {
        bf16x8 t;
#pragma unroll
        for (int e = 0; e < 8; ++e)
          t[e] = (short)v_lds[wid][(kf * 32 + lg * 8 + e) * 40 + df * 16 + li];
        bv[df] = t;
      }
#pragma unroll
      for (int mf = 0; mf < 4; ++mf) {
        bf16x8 pa = *(const bf16x8*)&p_lds[wid][(mf * 16 + li) * 72 + kf * 32 + lg * 8];
#pragma unroll
        for (int df = 0; df < 2; ++df)
          o[mf][df] = __builtin_amdgcn_mfma_f32_16x16x32_bf16(pa, bv[df], o[mf][df], 0, 0, 0);
      }
    }

#pragma unroll
    for (int mf = 0; mf < 4; ++mf)
#pragma unroll
      for (int df = 0; df < 2; ++df)
#pragma unroll
        for (int r = 0; r < 4; ++r) {
          size_t row = base + mf * 16 + lg * 4 + r;
          out[row * 384 + h * 32 + df * 16 + li] = f2bf(o[mf][df][r]);
        }
  }
}

extern "C" void kernel_launch(void* const* d_in, const int* in_sizes, int n_in,
                              void* d_out, int out_size, void* d_ws, size_t ws_size,
                              hipStream_t stream) {
  const float* x      = (const float*)d_in[0];
  const float* qkv_w  = (const float*)d_in[1];
  const float* qkv_b  = (const float*)d_in[2];
  const float* proj_w = (const float*)d_in[3];
  const float* proj_b = (const float*)d_in[4];
  const float* rel    = (const float*)d_in[5];
  const float* g1     = (const float*)d_in[6];
  const float* b1     = (const float*)d_in[7];
  const float* g2     = (const float*)d_in[8];
  const float* b2     = (const float*)d_in[9];
  const float* fc1_w  = (const float*)d_in[10];
  const float* fc1_b  = (const float*)d_in[11];
  const float* fc2_w  = (const float*)d_in[12];
  const float* fc2_b  = (const float*)d_in[13];
  const float* mask   = (const float*)d_in[14];
  float* out = (float*)d_out;
  char* ws = (char*)d_ws;

  const int M = 131072;  // B * H * W tokens
  unsigned short* hw     = (unsigned short*)ws;
  unsigned short* qkv    = (unsigned short*)(ws + 100663296);
  unsigned short* hmid   = (unsigned short*)ws;
  unsigned short* attn_o = (unsigned short*)(ws + 402653184);
  unsigned short* ln2o   = attn_o;
  float*          x1     = (float*)(ws + 503316480);
  unsigned short* wq     = (unsigned short*)(ws + 704643072);
  unsigned short* wp     = wq + 442368;
  unsigned short* w1     = wp + 147456;
  unsigned short* w2     = w1 + 589824;

  cvt_f32_bf16<<<(442368 + 255) / 256, 256, 0, stream>>>(qkv_w, wq, 442368);
  cvt_f32_bf16<<<(147456 + 255) / 256, 256, 0, stream>>>(proj_w, wp, 147456);
  cvt_f32_bf16<<<(589824 + 255) / 256, 256, 0, stream>>>(fc1_w, w1, 589824);
  cvt_f32_bf16<<<(589824 + 255) / 256, 256, 0, stream>>>(fc2_w, w2, 589824);

  // LN1 + shift + window partition
  ln_kernel<1><<<M / 4, 256, 0, stream>>>(x, g1, b1, hw);

  // QKV projection (grid linearized: wg = mtile*NT + ntile)
  gemm_bt<0><<<9 * 1024, 256, 0, stream>>>(hw, wq, qkv_b, M, 1152, 384, 9, qkv, nullptr, nullptr);

  // windowed attention
  attn_kernel<<<2048, 256, 0, stream>>>(qkv, rel, mask, attn_o);

  // proj + window reverse + unshift + residual -> x1
  gemm_bt<2><<<3 * 1024, 256, 0, stream>>>(attn_o, wp, proj_b, M, 384, 384, 3, nullptr, x, x1);

  // LN2
  ln_kernel<0><<<M / 4, 256, 0, stream>>>(x1, g2, b2, ln2o);

  // FC1 + GELU
  gemm_bt<1><<<12 * 1024, 256, 0, stream>>>(ln2o, w1, fc1_b, M, 1536, 384, 12, hmid, nullptr, nullptr);

  // FC2 + residual -> out
  gemm_bt<3><<<3 * 1024, 256, 0, stream>>>(hmid, w2, fc2_b, M, 384, 1536, 3, nullptr, x1, out);
}

// Round 4
// 1240.587 us; speedup vs baseline: 1.2167x; 1.0320x over previous
//
#include <hip/hip_runtime.h>
#include <hip/hip_bf16.h>
#include <math.h>

typedef __attribute__((ext_vector_type(4))) float f32x4;
typedef __attribute__((ext_vector_type(8))) short bf16x8;

__device__ __forceinline__ unsigned short f2bf(float f) {
  unsigned int x = __builtin_bit_cast(unsigned int, f);
  x += 0x7fffu + ((x >> 16) & 1u);
  return (unsigned short)(x >> 16);
}

__device__ __forceinline__ void gload_lds16(const void* g, void* l) {
  __builtin_amdgcn_global_load_lds(
      (const __attribute__((address_space(1))) unsigned int*)g,
      (__attribute__((address_space(3))) unsigned int*)l, 16, 0, 0);
}

// ---------------- f32 -> bf16 cast ----------------
__global__ void cvt_f32_bf16(const float* __restrict__ s, unsigned short* __restrict__ d, int n) {
  int i = blockIdx.x * 256 + threadIdx.x;
  if (i < n) d[i] = f2bf(s[i]);
}

// ---------------- LayerNorm (optionally with shift+window gather) ----------------
template <int REMAP>
__global__ __launch_bounds__(256)
void ln_kernel(const float* __restrict__ x, const float* __restrict__ g,
               const float* __restrict__ b, unsigned short* __restrict__ dst_o) {
  int r = blockIdx.x * 4 + (threadIdx.x >> 6);
  int lane = threadIdx.x & 63;
  size_t src;
  if (REMAP) {
    int w = r >> 6, t = r & 63;
    int bb = w >> 8, wi = (w >> 4) & 15, wj = w & 15;
    int i = t >> 3, j = t & 7;
    int p = (wi * 8 + i + 4) & 127, q = (wj * 8 + j + 4) & 127;
    src = ((size_t)bb * 16384 + p * 128 + q) * 384;
  } else {
    src = (size_t)r * 384;
  }
  float v[6];
  float s = 0.f, s2 = 0.f;
#pragma unroll
  for (int m = 0; m < 6; ++m) {
    v[m] = x[src + lane + 64 * m];
    s += v[m];
    s2 += v[m] * v[m];
  }
#pragma unroll
  for (int o2 = 1; o2 < 64; o2 <<= 1) {
    s += __shfl_xor(s, o2);
    s2 += __shfl_xor(s2, o2);
  }
  float mu = s * (1.f / 384.f);
  float var = s2 * (1.f / 384.f) - mu * mu;
  float ri = rsqrtf(var + 1e-5f);
  size_t dst = (size_t)r * 384;
#pragma unroll
  for (int m = 0; m < 6; ++m) {
    int c = lane + 64 * m;
    dst_o[dst + c] = f2bf((v[m] - mu) * ri * g[c] + b[c]);
  }
}

// ---------------- GEMM: C(M,N) = A(M,K) * B(N,K)^T ----------------
// A,B staged via global_load_lds (linear LDS dest, PRE-SWIZZLED global source);
// fragment ds_reads XOR-swizzled to kill the 16-way bank conflict of row-major
// [128][64] bf16 tiles (T2, rule #21 both-sides). 2-phase double-buffer,
// one __syncthreads per K-step. Linearized grid + bijective XCD swizzle.
// Swizzle involution (elements): col' = col ^ ((row & 7) << 3).
// EPI 0: out = bf16(acc + bias)                       -> Obf
// EPI 1: out = bf16(gelu_tanh(acc + bias))            -> Obf
// EPI 2: proj: scatter window->image, += resid(x)     -> Of (f32)
// EPI 3: out = acc + bias + resid                     -> Of (f32)
template <int EPI>
__global__ __launch_bounds__(256, 2)
void gemm_bt(const unsigned short* __restrict__ A, const unsigned short* __restrict__ Bw,
             const float* __restrict__ bias, int M, int N, int K, int NT,
             unsigned short* __restrict__ Obf, const float* __restrict__ resid,
             float* __restrict__ Of) {
  __shared__ unsigned short smA[2][128 * 64];
  __shared__ unsigned short smB[2][128 * 64];
  const int tid = threadIdx.x;
  const int lane = tid & 63;
  const int wid = tid >> 6;
  const int wm = wid >> 1, wn = wid & 1;
  const int li = lane & 15, lg = lane >> 4;

  // bijective XCD swizzle (m204)
  const int nwg = gridDim.x;
  const int orig = blockIdx.x;
  const int q = nwg >> 3, r = nwg & 7;
  const int xcd = orig & 7, loc = orig >> 3;
  const int wg = (xcd < r ? xcd * (q + 1) : r * (q + 1) + (xcd - r) * q) + loc;
  const int m0 = (wg / NT) * 128;
  const int n0 = (wg % NT) * 128;

  // staging: LDS dest is linear (gload_lds writes base + lane*16); the staged
  // row within the tile has row&7 == lane>>3, so the inverse-swizzled global
  // source column is ((lane&7) ^ (lane>>3)) * 8 elements.
  const int srow = wid * 32 + (lane >> 3);
  const int scol = ((lane & 7) ^ (lane >> 3)) * 8;
  const unsigned short* gA = A + (size_t)(m0 + srow) * K + scol;
  const unsigned short* gB = Bw + (size_t)(n0 + srow) * K + scol;

  f32x4 acc[4][4] = {};
  const int nk = K >> 6;

  // fragment read offsets (swizzled): row&7 == li&7 for both A and B frags
  const int fswz = (li & 7) << 3;

  // prologue: stage K-step 0 into buffer 0
#pragma unroll
  for (int c = 0; c < 4; ++c) {
    gload_lds16(gA + (size_t)(c * 8) * K, &smA[0][(wid * 32 + c * 8) * 64]);
    gload_lds16(gB + (size_t)(c * 8) * K, &smB[0][(wid * 32 + c * 8) * 64]);
  }
  __syncthreads();

  for (int k0 = 0; k0 < nk; ++k0) {
    const int cur = k0 & 1;
    if (k0 + 1 < nk) {
#pragma unroll
      for (int c = 0; c < 4; ++c) {
        gload_lds16(gA + (size_t)(c * 8) * K + (k0 + 1) * 64,
                    &smA[cur ^ 1][(wid * 32 + c * 8) * 64]);
        gload_lds16(gB + (size_t)(c * 8) * K + (k0 + 1) * 64,
                    &smB[cur ^ 1][(wid * 32 + c * 8) * 64]);
      }
    }
#pragma unroll
    for (int kk = 0; kk < 2; ++kk) {
      bf16x8 a[4], bb[4];
#pragma unroll
      for (int f = 0; f < 4; ++f) {
        a[f] = *(const bf16x8*)&smA[cur][(wm * 64 + f * 16 + li) * 64 + ((kk * 32 + lg * 8) ^ fswz)];
        bb[f] = *(const bf16x8*)&smB[cur][(wn * 64 + f * 16 + li) * 64 + ((kk * 32 + lg * 8) ^ fswz)];
      }
#pragma unroll
      for (int mf = 0; mf < 4; ++mf)
#pragma unroll
        for (int nf = 0; nf < 4; ++nf)
          acc[mf][nf] = __builtin_amdgcn_mfma_f32_16x16x32_bf16(a[mf], bb[nf], acc[mf][nf], 0, 0, 0);
    }
    __syncthreads();
  }

  // epilogue: C/D layout col = lane&15, row = (lane>>4)*4 + reg
#pragma unroll
  for (int mf = 0; mf < 4; ++mf) {
#pragma unroll
    for (int r2 = 0; r2 < 4; ++r2) {
      int mrow = m0 + wm * 64 + mf * 16 + lg * 4 + r2;
      size_t orow = (size_t)mrow;
      if (EPI == 2) {
        int w = mrow >> 6, t = mrow & 63;
        int bb2 = w >> 8, wi = (w >> 4) & 15, wj = w & 15;
        int i = t >> 3, j = t & 7;
        int p = (wi * 8 + i + 4) & 127, qq = (wj * 8 + j + 4) & 127;
        orow = (size_t)bb2 * 16384 + p * 128 + qq;
      }
#pragma unroll
      for (int nf = 0; nf < 4; ++nf) {
        int col = n0 + wn * 64 + nf * 16 + li;
        float v = acc[mf][nf][r2] + bias[col];
        if (EPI == 0) {
          Obf[(size_t)mrow * N + col] = f2bf(v);
        } else if (EPI == 1) {
          // tanh-form GELU via sigmoid: v * sigma(1.5957691*(v + 0.044715 v^3))
          float y = 1.5957691f * (v + 0.044715f * v * v * v);
          float gl = v / (1.f + __expf(-y));
          Obf[(size_t)mrow * N + col] = f2bf(gl);
        } else if (EPI == 2) {
          Of[orow * 384 + col] = v + resid[orow * 384 + col];
        } else {
          Of[(size_t)mrow * N + col] = v + resid[(size_t)mrow * N + col];
        }
      }
    }
  }
}

// ---------------- windowed attention: one block per window, 4 waves x 3 heads ----------------
__global__ __launch_bounds__(256, 2)
void attn_kernel(const unsigned short* __restrict__ qkv, const float* __restrict__ btab,
                 const float* __restrict__ mask, unsigned short* __restrict__ out) {
  __shared__ unsigned short v_lds[4][64 * 40];  // V tile, row stride 40
  __shared__ unsigned short p_lds[4][64 * 72];  // P tile, row stride 72
  const int w = blockIdx.x;
  const int tid = threadIdx.x;
  const int wid = tid >> 6, lane = tid & 63;
  const int li = lane & 15, lg = lane >> 4;
  const float* mrow = mask + (size_t)(w & 255) * 4096;
  const size_t base = (size_t)w * 64;
  const float SC = 0.17677669529663688f;  // 32^-0.5

#pragma unroll 1
  for (int hi = 0; hi < 3; ++hi) {
    int h = wid * 3 + hi;
    bf16x8 aq[4], bk[4];
#pragma unroll
    for (int f = 0; f < 4; ++f) {
      size_t off = (base + f * 16 + li) * 1152 + h * 32 + lg * 8;
      aq[f] = *(const bf16x8*)&qkv[off];
      bk[f] = *(const bf16x8*)&qkv[off + 384];
    }
    f32x4 s[4][4] = {};
#pragma unroll
    for (int mf = 0; mf < 4; ++mf)
#pragma unroll
      for (int nf = 0; nf < 4; ++nf)
        s[mf][nf] = __builtin_amdgcn_mfma_f32_16x16x32_bf16(aq[mf], bk[nf], s[mf][nf], 0, 0, 0);

    {
      const unsigned short* vp = &qkv[(base + lane) * 1152 + 768 + h * 32];
      unsigned short* dp = &v_lds[wid][lane * 40];
#pragma unroll
      for (int c = 0; c < 4; ++c) *(bf16x8*)&dp[c * 8] = *(const bf16x8*)&vp[c * 8];
    }

#pragma unroll
    for (int mf = 0; mf < 4; ++mf) {
#pragma unroll
      for (int r = 0; r < 4; ++r) {
        int m = mf * 16 + lg * 4 + r;
        float mx = -1e30f;
#pragma unroll
        for (int nf = 0; nf < 4; ++nf) {
          int n = nf * 16 + li;
          int ridx = ((m >> 3) - (n >> 3) + 7) * 15 + (m & 7) - (n & 7) + 7;
          float val = s[mf][nf][r] * SC + btab[ridx * 12 + h] + mrow[m * 64 + n];
          s[mf][nf][r] = val;
          mx = fmaxf(mx, val);
        }
#pragma unroll
        for (int o2 = 1; o2 < 16; o2 <<= 1) mx = fmaxf(mx, __shfl_xor(mx, o2));
        float sum = 0.f;
#pragma unroll
        for (int nf = 0; nf < 4; ++nf) {
          float e = __expf(s[mf][nf][r] - mx);
          s[mf][nf][r] = e;
          sum += e;
        }
#pragma unroll
        for (int o2 = 1; o2 < 16; o2 <<= 1) sum += __shfl_xor(sum, o2);
        float inv = 1.f / sum;
#pragma unroll
        for (int nf = 0; nf < 4; ++nf) s[mf][nf][r] *= inv;
      }
    }

#pragma unroll
    for (int mf = 0; mf < 4; ++mf)
#pragma unroll
      for (int nf = 0; nf < 4; ++nf)
#pragma unroll
        for (int r = 0; r < 4; ++r) {
          int m = mf * 16 + lg * 4 + r, n = nf * 16 + li;
          p_lds[wid][m * 72 + n] = f2bf(s[mf][nf][r]);
        }

    f32x4 o[4][2] = {};
#pragma unroll
    for (int kf = 0; kf < 2; ++kf) {
      bf16x8 bv[2];
#pragma unroll
      for (int df = 0; df < 2; ++df) {
        bf16x8 t;
#pragma unroll
        for (int e = 0; e < 8; ++e)
          t[e] = (short)v_lds[wid][(kf * 32 + lg * 8 + e) * 40 + df * 16 + li];
        bv[df] = t;
      }
#pragma unroll
      for (int mf = 0; mf < 4; ++mf) {
        bf16x8 pa = *(const bf16x8*)&p_lds[wid][(mf * 16 + li) * 72 + kf * 32 + lg * 8];
#pragma unroll
        for (int df = 0; df < 2; ++df)
          o[mf][df] = __builtin_amdgcn_mfma_f32_16x16x32_bf16(pa, bv[df], o[mf][df], 0, 0, 0);
      }
    }

#pragma unroll
    for (int mf = 0; mf < 4; ++mf)
#pragma unroll
      for (int df = 0; df < 2; ++df)
#pragma unroll
        for (int r = 0; r < 4; ++r) {
          size_t row = base + mf * 16 + lg * 4 + r;
          out[row * 384 + h * 32 + df * 16 + li] = f2bf(o[mf][df][r]);
        }
  }
}

extern "C" void kernel_launch(void* const* d_in, const int* in_sizes, int n_in,
                              void* d_out, int out_size, void* d_ws, size_t ws_size,
                              hipStream_t stream) {
  const float* x      = (const float*)d_in[0];
  const float* qkv_w  = (const float*)d_in[1];
  const float* qkv_b  = (const float*)d_in[2];
  const float* proj_w = (const float*)d_in[3];
  const float* proj_b = (const float*)d_in[4];
  const float* rel    = (const float*)d_in[5];
  const float* g1     = (const float*)d_in[6];
  const float* b1     = (const float*)d_in[7];
  const float* g2     = (const float*)d_in[8];
  const float* b2     = (const float*)d_in[9];
  const float* fc1_w  = (const float*)d_in[10];
  const float* fc1_b  = (const float*)d_in[11];
  const float* fc2_w  = (const float*)d_in[12];
  const float* fc2_b  = (const float*)d_in[13];
  const float* mask   = (const float*)d_in[14];
  float* out = (float*)d_out;
  char* ws = (char*)d_ws;

  const int M = 131072;  // B * H * W tokens
  unsigned short* hw     = (unsigned short*)ws;
  unsigned short* qkv    = (unsigned short*)(ws + 100663296);
  unsigned short* hmid   = (unsigned short*)ws;
  unsigned short* attn_o = (unsigned short*)(ws + 402653184);
  unsigned short* ln2o   = attn_o;
  float*          x1     = (float*)(ws + 503316480);
  unsigned short* wq     = (unsigned short*)(ws + 704643072);
  unsigned short* wp     = wq + 442368;
  unsigned short* w1     = wp + 147456;
  unsigned short* w2     = w1 + 589824;

  cvt_f32_bf16<<<(442368 + 255) / 256, 256, 0, stream>>>(qkv_w, wq, 442368);
  cvt_f32_bf16<<<(147456 + 255) / 256, 256, 0, stream>>>(proj_w, wp, 147456);
  cvt_f32_bf16<<<(589824 + 255) / 256, 256, 0, stream>>>(fc1_w, w1, 589824);
  cvt_f32_bf16<<<(589824 + 255) / 256, 256, 0, stream>>>(fc2_w, w2, 589824);

  // LN1 + shift + window partition
  ln_kernel<1><<<M / 4, 256, 0, stream>>>(x, g1, b1, hw);

  // QKV projection (grid linearized: wg = mtile*NT + ntile)
  gemm_bt<0><<<9 * 1024, 256, 0, stream>>>(hw, wq, qkv_b, M, 1152, 384, 9, qkv, nullptr, nullptr);

  // windowed attention
  attn_kernel<<<2048, 256, 0, stream>>>(qkv, rel, mask, attn_o);

  // proj + window reverse + unshift + residual -> x1
  gemm_bt<2><<<3 * 1024, 256, 0, stream>>>(attn_o, wp, proj_b, M, 384, 384, 3, nullptr, x, x1);

  // LN2
  ln_kernel<0><<<M / 4, 256, 0, stream>>>(x1, g2, b2, ln2o);

  // FC1 + GELU
  gemm_bt<1><<<12 * 1024, 256, 0, stream>>>(ln2o, w1, fc1_b, M, 1536, 384, 12, hmid, nullptr, nullptr);

  // FC2 + residual -> out
  gemm_bt<3><<<3 * 1024, 256, 0, stream>>>(hmid, w2, fc2_b, M, 384, 1536, 3, nullptr, x1, out);
}

// Round 5
// 1232.948 us; speedup vs baseline: 1.2242x; 1.0062x over previous
//
#include <hip/hip_runtime.h>
#include <hip/hip_bf16.h>
#include <math.h>

typedef __attribute__((ext_vector_type(4))) float f32x4;
typedef __attribute__((ext_vector_type(8))) short bf16x8;

__device__ __forceinline__ unsigned short f2bf(float f) {
  unsigned int x = __builtin_bit_cast(unsigned int, f);
  x += 0x7fffu + ((x >> 16) & 1u);
  return (unsigned short)(x >> 16);
}
__device__ __forceinline__ float bf2f(unsigned short u) {
  unsigned int x = ((unsigned int)u) << 16;
  return __builtin_bit_cast(float, x);
}

__device__ __forceinline__ void gload_lds16(const void* g, void* l) {
  __builtin_amdgcn_global_load_lds(
      (const __attribute__((address_space(1))) unsigned int*)g,
      (__attribute__((address_space(3))) unsigned int*)l, 16, 0, 0);
}

// ---------------- f32 -> bf16 cast ----------------
__global__ void cvt_f32_bf16(const float* __restrict__ s, unsigned short* __restrict__ d, int n) {
  int i = blockIdx.x * 256 + threadIdx.x;
  if (i < n) d[i] = f2bf(s[i]);
}

// ---------------- LayerNorm, f32 input (optional shift+window gather) ----------------
template <int REMAP>
__global__ __launch_bounds__(256)
void ln_kernel(const float* __restrict__ x, const float* __restrict__ g,
               const float* __restrict__ b, unsigned short* __restrict__ dst_o) {
  int r = blockIdx.x * 4 + (threadIdx.x >> 6);
  int lane = threadIdx.x & 63;
  size_t src;
  if (REMAP) {
    int w = r >> 6, t = r & 63;
    int bb = w >> 8, wi = (w >> 4) & 15, wj = w & 15;
    int i = t >> 3, j = t & 7;
    int p = (wi * 8 + i + 4) & 127, q = (wj * 8 + j + 4) & 127;
    src = ((size_t)bb * 16384 + p * 128 + q) * 384;
  } else {
    src = (size_t)r * 384;
  }
  float v[6];
  float s = 0.f, s2 = 0.f;
#pragma unroll
  for (int m = 0; m < 6; ++m) {
    v[m] = x[src + lane + 64 * m];
    s += v[m];
    s2 += v[m] * v[m];
  }
#pragma unroll
  for (int o2 = 1; o2 < 64; o2 <<= 1) {
    s += __shfl_xor(s, o2);
    s2 += __shfl_xor(s2, o2);
  }
  float mu = s * (1.f / 384.f);
  float var = s2 * (1.f / 384.f) - mu * mu;
  float ri = rsqrtf(var + 1e-5f);
  size_t dst = (size_t)r * 384;
#pragma unroll
  for (int m = 0; m < 6; ++m) {
    int c = lane + 64 * m;
    dst_o[dst + c] = f2bf((v[m] - mu) * ri * g[c] + b[c]);
  }
}

// ---------------- LayerNorm, bf16 input (for LN2 on bf16 x1) ----------------
__global__ __launch_bounds__(256)
void ln_bf16(const unsigned short* __restrict__ x, const float* __restrict__ g,
             const float* __restrict__ b, unsigned short* __restrict__ dst_o) {
  int r = blockIdx.x * 4 + (threadIdx.x >> 6);
  int lane = threadIdx.x & 63;
  size_t src = (size_t)r * 384;
  float v[6];
  float s = 0.f, s2 = 0.f;
#pragma unroll
  for (int m = 0; m < 3; ++m) {
    unsigned int u = *(const unsigned int*)&x[src + lane * 2 + 128 * m];
    v[2 * m] = bf2f((unsigned short)(u & 0xffffu));
    v[2 * m + 1] = bf2f((unsigned short)(u >> 16));
    s += v[2 * m] + v[2 * m + 1];
    s2 += v[2 * m] * v[2 * m] + v[2 * m + 1] * v[2 * m + 1];
  }
#pragma unroll
  for (int o2 = 1; o2 < 64; o2 <<= 1) {
    s += __shfl_xor(s, o2);
    s2 += __shfl_xor(s2, o2);
  }
  float mu = s * (1.f / 384.f);
  float var = s2 * (1.f / 384.f) - mu * mu;
  float ri = rsqrtf(var + 1e-5f);
#pragma unroll
  for (int m = 0; m < 3; ++m) {
    int c = lane * 2 + 128 * m;
    unsigned int lo = f2bf((v[2 * m] - mu) * ri * g[c] + b[c]);
    unsigned int hi = f2bf((v[2 * m + 1] - mu) * ri * g[c + 1] + b[c + 1]);
    *(unsigned int*)&dst_o[src + c] = lo | (hi << 16);
  }
}

// ---------------- GEMM: C(M,N) = A(M,K) * B(N,K)^T ----------------
// 512 threads, 8 waves (2x4), 128x128 tile, BK=64. A,B staged via
// global_load_lds (linear dest, pre-swizzled global source col); fragment
// ds_reads XOR-swizzled (T2 both-sides, conflict-free, verified R4).
// 2-phase double buffer, one __syncthreads per K-step. Bijective XCD swizzle.
// EPI 0: out = bf16(acc + bias)                         -> Obf
// EPI 1: out = bf16(gelu_tanh(acc + bias))              -> Obf
// EPI 2: proj: scatter window->image, bf16(v + x_f32)   -> Obf (x1 bf16)
// EPI 3: out = acc + bias + bf16resid                   -> Of (f32)
template <int EPI>
__global__ __launch_bounds__(512, 2)
void gemm_bt(const unsigned short* __restrict__ A, const unsigned short* __restrict__ Bw,
             const float* __restrict__ bias, int M, int N, int K, int NT,
             unsigned short* __restrict__ Obf, const void* __restrict__ resid,
             float* __restrict__ Of) {
  __shared__ unsigned short smA[2][128 * 64];
  __shared__ unsigned short smB[2][128 * 64];
  const int tid = threadIdx.x;
  const int lane = tid & 63;
  const int wid = tid >> 6;          // 0..7
  const int wm = wid >> 2, wn = wid & 3;  // wave grid 2x4; wave output 64x32
  const int li = lane & 15, lg = lane >> 4;

  // bijective XCD swizzle (m204)
  const int nwg = gridDim.x;
  const int orig = blockIdx.x;
  const int q = nwg >> 3, r = nwg & 7;
  const int xcd = orig & 7, loc = orig >> 3;
  const int wg = (xcd < r ? xcd * (q + 1) : r * (q + 1) + (xcd - r) * q) + loc;
  const int m0 = (wg / NT) * 128;
  const int n0 = (wg % NT) * 128;

  // staging: 512 threads x 16B = 8KB = 64 rows; c in {0,1} covers 128 rows.
  // linear LDS dest; inverse-swizzled global source column (row&7 == lane>>3).
  const int srow = wid * 8 + (lane >> 3);            // 0..63
  const int scol = ((lane & 7) ^ (lane >> 3)) * 8;   // pre-swizzled col
  const unsigned short* gA = A + (size_t)(m0 + srow) * K + scol;
  const unsigned short* gB = Bw + (size_t)(n0 + srow) * K + scol;

  f32x4 acc[4][2] = {};
  const int nk = K >> 6;
  const int fswz = (li & 7) << 3;  // fragment read swizzle (row&7 == li&7)

  // prologue: stage K-step 0 into buffer 0
#pragma unroll
  for (int c = 0; c < 2; ++c) {
    gload_lds16(gA + (size_t)(c * 64) * K, &smA[0][c * 4096 + wid * 512]);
    gload_lds16(gB + (size_t)(c * 64) * K, &smB[0][c * 4096 + wid * 512]);
  }
  __syncthreads();

  for (int k0 = 0; k0 < nk; ++k0) {
    const int cur = k0 & 1;
    if (k0 + 1 < nk) {
#pragma unroll
      for (int c = 0; c < 2; ++c) {
        gload_lds16(gA + (size_t)(c * 64) * K + (k0 + 1) * 64,
                    &smA[cur ^ 1][c * 4096 + wid * 512]);
        gload_lds16(gB + (size_t)(c * 64) * K + (k0 + 1) * 64,
                    &smB[cur ^ 1][c * 4096 + wid * 512]);
      }
    }
#pragma unroll
    for (int kk = 0; kk < 2; ++kk) {
      bf16x8 a[4], bb[2];
#pragma unroll
      for (int f = 0; f < 4; ++f)
        a[f] = *(const bf16x8*)&smA[cur][(wm * 64 + f * 16 + li) * 64 + ((kk * 32 + lg * 8) ^ fswz)];
#pragma unroll
      for (int f = 0; f < 2; ++f)
        bb[f] = *(const bf16x8*)&smB[cur][(wn * 32 + f * 16 + li) * 64 + ((kk * 32 + lg * 8) ^ fswz)];
#pragma unroll
      for (int mf = 0; mf < 4; ++mf)
#pragma unroll
        for (int nf = 0; nf < 2; ++nf)
          acc[mf][nf] = __builtin_amdgcn_mfma_f32_16x16x32_bf16(a[mf], bb[nf], acc[mf][nf], 0, 0, 0);
    }
    __syncthreads();
  }

  // epilogue: C/D layout col = lane&15, row = (lane>>4)*4 + reg
#pragma unroll
  for (int mf = 0; mf < 4; ++mf) {
#pragma unroll
    for (int r2 = 0; r2 < 4; ++r2) {
      int mrow = m0 + wm * 64 + mf * 16 + lg * 4 + r2;
      size_t orow = (size_t)mrow;
      if (EPI == 2) {
        int w = mrow >> 6, t = mrow & 63;
        int bb2 = w >> 8, wi = (w >> 4) & 15, wj = w & 15;
        int i = t >> 3, j = t & 7;
        int p = (wi * 8 + i + 4) & 127, qq = (wj * 8 + j + 4) & 127;
        orow = (size_t)bb2 * 16384 + p * 128 + qq;
      }
#pragma unroll
      for (int nf = 0; nf < 2; ++nf) {
        int col = n0 + wn * 32 + nf * 16 + li;
        float v = acc[mf][nf][r2] + bias[col];
        if (EPI == 0) {
          Obf[(size_t)mrow * N + col] = f2bf(v);
        } else if (EPI == 1) {
          float y = 1.5957691f * (v + 0.044715f * v * v * v);
          float gl = v / (1.f + __expf(-y));
          Obf[(size_t)mrow * N + col] = f2bf(gl);
        } else if (EPI == 2) {
          const float* rx = (const float*)resid;
          Obf[orow * 384 + col] = f2bf(v + rx[orow * 384 + col]);
        } else {
          const unsigned short* rx = (const unsigned short*)resid;
          Of[(size_t)mrow * N + col] = v + bf2f(rx[(size_t)mrow * N + col]);
        }
      }
    }
  }
}

// ---------------- windowed attention: one block per window, 4 waves x 3 heads ----------------
__global__ __launch_bounds__(256, 2)
void attn_kernel(const unsigned short* __restrict__ qkv, const float* __restrict__ btab,
                 const float* __restrict__ mask, unsigned short* __restrict__ out) {
  __shared__ unsigned short v_lds[4][64 * 40];  // V tile, row stride 40
  __shared__ unsigned short p_lds[4][64 * 72];  // P tile, row stride 72
  const int w = blockIdx.x;
  const int tid = threadIdx.x;
  const int wid = tid >> 6, lane = tid & 63;
  const int li = lane & 15, lg = lane >> 4;
  const float* mrow = mask + (size_t)(w & 255) * 4096;
  const size_t base = (size_t)w * 64;
  const float SC = 0.17677669529663688f;  // 32^-0.5

#pragma unroll 1
  for (int hi = 0; hi < 3; ++hi) {
    int h = wid * 3 + hi;
    bf16x8 aq[4], bk[4];
#pragma unroll
    for (int f = 0; f < 4; ++f) {
      size_t off = (base + f * 16 + li) * 1152 + h * 32 + lg * 8;
      aq[f] = *(const bf16x8*)&qkv[off];
      bk[f] = *(const bf16x8*)&qkv[off + 384];
    }
    f32x4 s[4][4] = {};
#pragma unroll
    for (int mf = 0; mf < 4; ++mf)
#pragma unroll
      for (int nf = 0; nf < 4; ++nf)
        s[mf][nf] = __builtin_amdgcn_mfma_f32_16x16x32_bf16(aq[mf], bk[nf], s[mf][nf], 0, 0, 0);

    {
      const unsigned short* vp = &qkv[(base + lane) * 1152 + 768 + h * 32];
      unsigned short* dp = &v_lds[wid][lane * 40];
#pragma unroll
      for (int c = 0; c < 4; ++c) *(bf16x8*)&dp[c * 8] = *(const bf16x8*)&vp[c * 8];
    }

#pragma unroll
    for (int mf = 0; mf < 4; ++mf) {
#pragma unroll
      for (int r = 0; r < 4; ++r) {
        int m = mf * 16 + lg * 4 + r;
        float mx = -1e30f;
#pragma unroll
        for (int nf = 0; nf < 4; ++nf) {
          int n = nf * 16 + li;
          int ridx = ((m >> 3) - (n >> 3) + 7) * 15 + (m & 7) - (n & 7) + 7;
          float val = s[mf][nf][r] * SC + btab[ridx * 12 + h] + mrow[m * 64 + n];
          s[mf][nf][r] = val;
          mx = fmaxf(mx, val);
        }
#pragma unroll
        for (int o2 = 1; o2 < 16; o2 <<= 1) mx = fmaxf(mx, __shfl_xor(mx, o2));
        float sum = 0.f;
#pragma unroll
        for (int nf = 0; nf < 4; ++nf) {
          float e = __expf(s[mf][nf][r] - mx);
          s[mf][nf][r] = e;
          sum += e;
        }
#pragma unroll
        for (int o2 = 1; o2 < 16; o2 <<= 1) sum += __shfl_xor(sum, o2);
        float inv = 1.f / sum;
#pragma unroll
        for (int nf = 0; nf < 4; ++nf) s[mf][nf][r] *= inv;
      }
    }

#pragma unroll
    for (int mf = 0; mf < 4; ++mf)
#pragma unroll
      for (int nf = 0; nf < 4; ++nf)
#pragma unroll
        for (int r = 0; r < 4; ++r) {
          int m = mf * 16 + lg * 4 + r, n = nf * 16 + li;
          p_lds[wid][m * 72 + n] = f2bf(s[mf][nf][r]);
        }

    f32x4 o[4][2] = {};
#pragma unroll
    for (int kf = 0; kf < 2; ++kf) {
      bf16x8 bv[2];
#pragma unroll
      for (int df = 0; df < 2; ++df) {
        bf16x8 t;
#pragma unroll
        for (int e = 0; e < 8; ++e)
          t[e] = (short)v_lds[wid][(kf * 32 + lg * 8 + e) * 40 + df * 16 + li];
        bv[df] = t;
      }
#pragma unroll
      for (int mf = 0; mf < 4; ++mf) {
        bf16x8 pa = *(const bf16x8*)&p_lds[wid][(mf * 16 + li) * 72 + kf * 32 + lg * 8];
#pragma unroll
        for (int df = 0; df < 2; ++df)
          o[mf][df] = __builtin_amdgcn_mfma_f32_16x16x32_bf16(pa, bv[df], o[mf][df], 0, 0, 0);
      }
    }

#pragma unroll
    for (int mf = 0; mf < 4; ++mf)
#pragma unroll
      for (int df = 0; df < 2; ++df)
#pragma unroll
        for (int r = 0; r < 4; ++r) {
          size_t row = base + mf * 16 + lg * 4 + r;
          out[row * 384 + h * 32 + df * 16 + li] = f2bf(o[mf][df][r]);
        }
  }
}

extern "C" void kernel_launch(void* const* d_in, const int* in_sizes, int n_in,
                              void* d_out, int out_size, void* d_ws, size_t ws_size,
                              hipStream_t stream) {
  const float* x      = (const float*)d_in[0];
  const float* qkv_w  = (const float*)d_in[1];
  const float* qkv_b  = (const float*)d_in[2];
  const float* proj_w = (const float*)d_in[3];
  const float* proj_b = (const float*)d_in[4];
  const float* rel    = (const float*)d_in[5];
  const float* g1     = (const float*)d_in[6];
  const float* b1     = (const float*)d_in[7];
  const float* g2     = (const float*)d_in[8];
  const float* b2     = (const float*)d_in[9];
  const float* fc1_w  = (const float*)d_in[10];
  const float* fc1_b  = (const float*)d_in[11];
  const float* fc2_w  = (const float*)d_in[12];
  const float* fc2_b  = (const float*)d_in[13];
  const float* mask   = (const float*)d_in[14];
  float* out = (float*)d_out;
  char* ws = (char*)d_ws;

  const int M = 131072;  // B * H * W tokens
  // workspace (lifetime-overlapped):
  //   [0, 402653184):      hw bf16 (100 MB) + qkv bf16 (302 MB); reused as hmid bf16 (402 MB)
  //   [402653184, +100 MB): attn_o bf16; reused as ln2o bf16
  //   [503316480, +100 MB): x1 bf16
  //   [603979776, +3.4 MB): bf16 weights
  unsigned short* hw     = (unsigned short*)ws;
  unsigned short* qkv    = (unsigned short*)(ws + 100663296);
  unsigned short* hmid   = (unsigned short*)ws;
  unsigned short* attn_o = (unsigned short*)(ws + 402653184);
  unsigned short* ln2o   = attn_o;
  unsigned short* x1b    = (unsigned short*)(ws + 503316480);
  unsigned short* wq     = (unsigned short*)(ws + 603979776);
  unsigned short* wp     = wq + 442368;
  unsigned short* w1     = wp + 147456;
  unsigned short* w2     = w1 + 589824;

  cvt_f32_bf16<<<(442368 + 255) / 256, 256, 0, stream>>>(qkv_w, wq, 442368);
  cvt_f32_bf16<<<(147456 + 255) / 256, 256, 0, stream>>>(proj_w, wp, 147456);
  cvt_f32_bf16<<<(589824 + 255) / 256, 256, 0, stream>>>(fc1_w, w1, 589824);
  cvt_f32_bf16<<<(589824 + 255) / 256, 256, 0, stream>>>(fc2_w, w2, 589824);

  // LN1 + shift + window partition
  ln_kernel<1><<<M / 4, 256, 0, stream>>>(x, g1, b1, hw);

  // QKV projection
  gemm_bt<0><<<9 * 1024, 512, 0, stream>>>(hw, wq, qkv_b, M, 1152, 384, 9, qkv, nullptr, nullptr);

  // windowed attention
  attn_kernel<<<2048, 256, 0, stream>>>(qkv, rel, mask, attn_o);

  // proj + window reverse + unshift + residual(x f32) -> x1 (bf16)
  gemm_bt<2><<<3 * 1024, 512, 0, stream>>>(attn_o, wp, proj_b, M, 384, 384, 3, x1b, x, nullptr);

  // LN2 (bf16 in)
  ln_bf16<<<M / 4, 256, 0, stream>>>(x1b, g2, b2, ln2o);

  // FC1 + GELU
  gemm_bt<1><<<12 * 1024, 512, 0, stream>>>(ln2o, w1, fc1_b, M, 1536, 384, 12, hmid, nullptr, nullptr);

  // FC2 + residual(x1 bf16) -> out (f32)
  gemm_bt<3><<<3 * 1024, 512, 0, stream>>>(hmid, w2, fc2_b, M, 384, 1536, 3, nullptr, x1b, out);
}

// Round 6
// 1177.673 us; speedup vs baseline: 1.2817x; 1.0469x over previous
//
#include <hip/hip_runtime.h>
#include <hip/hip_bf16.h>
#include <math.h>

typedef __attribute__((ext_vector_type(4))) float f32x4;
typedef __attribute__((ext_vector_type(8))) short bf16x8;

__device__ __forceinline__ unsigned short f2bf(float f) {
  unsigned int x = __builtin_bit_cast(unsigned int, f);
  x += 0x7fffu + ((x >> 16) & 1u);
  return (unsigned short)(x >> 16);
}
__device__ __forceinline__ float bf2f(unsigned short u) {
  unsigned int x = ((unsigned int)u) << 16;
  return __builtin_bit_cast(float, x);
}

__device__ __forceinline__ void gload_lds16(const void* g, void* l) {
  __builtin_amdgcn_global_load_lds(
      (const __attribute__((address_space(1))) unsigned int*)g,
      (__attribute__((address_space(3))) unsigned int*)l, 16, 0, 0);
}

// ---------------- f32 -> bf16 cast ----------------
__global__ void cvt_f32_bf16(const float* __restrict__ s, unsigned short* __restrict__ d, int n) {
  int i = blockIdx.x * 256 + threadIdx.x;
  if (i < n) d[i] = f2bf(s[i]);
}

// ---------------- LayerNorm, f32 input (optional shift+window gather) ----------------
template <int REMAP>
__global__ __launch_bounds__(256)
void ln_kernel(const float* __restrict__ x, const float* __restrict__ g,
               const float* __restrict__ b, unsigned short* __restrict__ dst_o) {
  int r = blockIdx.x * 4 + (threadIdx.x >> 6);
  int lane = threadIdx.x & 63;
  size_t src;
  if (REMAP) {
    int w = r >> 6, t = r & 63;
    int bb = w >> 8, wi = (w >> 4) & 15, wj = w & 15;
    int i = t >> 3, j = t & 7;
    int p = (wi * 8 + i + 4) & 127, q = (wj * 8 + j + 4) & 127;
    src = ((size_t)bb * 16384 + p * 128 + q) * 384;
  } else {
    src = (size_t)r * 384;
  }
  float v[6];
  float s = 0.f, s2 = 0.f;
#pragma unroll
  for (int m = 0; m < 6; ++m) {
    v[m] = x[src + lane + 64 * m];
    s += v[m];
    s2 += v[m] * v[m];
  }
#pragma unroll
  for (int o2 = 1; o2 < 64; o2 <<= 1) {
    s += __shfl_xor(s, o2);
    s2 += __shfl_xor(s2, o2);
  }
  float mu = s * (1.f / 384.f);
  float var = s2 * (1.f / 384.f) - mu * mu;
  float ri = rsqrtf(var + 1e-5f);
  size_t dst = (size_t)r * 384;
#pragma unroll
  for (int m = 0; m < 6; ++m) {
    int c = lane + 64 * m;
    dst_o[dst + c] = f2bf((v[m] - mu) * ri * g[c] + b[c]);
  }
}

// ---------------- LayerNorm, bf16 input (for LN2 on bf16 x1) ----------------
__global__ __launch_bounds__(256)
void ln_bf16(const unsigned short* __restrict__ x, const float* __restrict__ g,
             const float* __restrict__ b, unsigned short* __restrict__ dst_o) {
  int r = blockIdx.x * 4 + (threadIdx.x >> 6);
  int lane = threadIdx.x & 63;
  size_t src = (size_t)r * 384;
  float v[6];
  float s = 0.f, s2 = 0.f;
#pragma unroll
  for (int m = 0; m < 3; ++m) {
    unsigned int u = *(const unsigned int*)&x[src + lane * 2 + 128 * m];
    v[2 * m] = bf2f((unsigned short)(u & 0xffffu));
    v[2 * m + 1] = bf2f((unsigned short)(u >> 16));
    s += v[2 * m] + v[2 * m + 1];
    s2 += v[2 * m] * v[2 * m] + v[2 * m + 1] * v[2 * m + 1];
  }
#pragma unroll
  for (int o2 = 1; o2 < 64; o2 <<= 1) {
    s += __shfl_xor(s, o2);
    s2 += __shfl_xor(s2, o2);
  }
  float mu = s * (1.f / 384.f);
  float var = s2 * (1.f / 384.f) - mu * mu;
  float ri = rsqrtf(var + 1e-5f);
#pragma unroll
  for (int m = 0; m < 3; ++m) {
    int c = lane * 2 + 128 * m;
    unsigned int lo = f2bf((v[2 * m] - mu) * ri * g[c] + b[c]);
    unsigned int hi = f2bf((v[2 * m + 1] - mu) * ri * g[c + 1] + b[c + 1]);
    *(unsigned int*)&dst_o[src + c] = lo | (hi << 16);
  }
}

// ---------------- GEMM: C(M,N) = A(M,K) * B(N,K)^T ----------------
// 256 threads, 4 waves (2x2 grid), wave tile 64x64 (acc[4][4]), block 128x128,
// BK=64. Per kk: 8 ds_read_b128 -> 16 MFMA (0.5 reads/MFMA). A,B staged via
// global_load_lds (linear dest, pre-swizzled source col); fragment reads
// XOR-swizzled (T2 both-sides, 0 conflicts verified R4). 2-phase double
// buffer, one __syncthreads per K-step. Bijective XCD swizzle (m204).
// EPI 0: out = bf16(acc + bias)                         -> Obf
// EPI 1: out = bf16(gelu_tanh(acc + bias))              -> Obf  (rcpf sigmoid)
// EPI 2: proj: scatter window->image, bf16(v + x_f32)   -> Obf (x1 bf16)
// EPI 3: out = acc + bias + bf16resid                   -> Of (f32)
template <int EPI>
__global__ __launch_bounds__(256, 2)
void gemm_bt(const unsigned short* __restrict__ A, const unsigned short* __restrict__ Bw,
             const float* __restrict__ bias, int M, int N, int K, int NT,
             unsigned short* __restrict__ Obf, const void* __restrict__ resid,
             float* __restrict__ Of) {
  __shared__ unsigned short smA[2][128 * 64];
  __shared__ unsigned short smB[2][128 * 64];
  const int tid = threadIdx.x;
  const int lane = tid & 63;
  const int wid = tid >> 6;               // 0..3
  const int wm = wid >> 1, wn = wid & 1;  // wave grid 2x2; wave output 64x64
  const int li = lane & 15, lg = lane >> 4;

  // bijective XCD swizzle (m204)
  const int nwg = gridDim.x;
  const int orig = blockIdx.x;
  const int q = nwg >> 3, r = nwg & 7;
  const int xcd = orig & 7, loc = orig >> 3;
  const int wg = (xcd < r ? xcd * (q + 1) : r * (q + 1) + (xcd - r) * q) + loc;
  const int m0 = (wg / NT) * 128;
  const int n0 = (wg % NT) * 128;

  // staging: per gload round, 4 waves x 1KB = 32 rows; 4 rounds each for A,B.
  // staged row = c*32 + wid*8 + (lane>>3)  ->  row&7 == lane>>3.
  // linear LDS dest; inverse-swizzled global source column.
  const int srow = wid * 8 + (lane >> 3);
  const int scol = ((lane & 7) ^ (lane >> 3)) * 8;
  const unsigned short* gA = A + (size_t)(m0 + srow) * K + scol;
  const unsigned short* gB = Bw + (size_t)(n0 + srow) * K + scol;

  f32x4 acc[4][4] = {};
  const int nk = K >> 6;
  const int fswz = (li & 7) << 3;  // fragment read swizzle (frag row&7 == li&7)

  // prologue: stage K-step 0 into buffer 0
#pragma unroll
  for (int c = 0; c < 4; ++c) {
    gload_lds16(gA + (size_t)(c * 32) * K, &smA[0][(c * 32 + wid * 8) * 64]);
    gload_lds16(gB + (size_t)(c * 32) * K, &smB[0][(c * 32 + wid * 8) * 64]);
  }
  __syncthreads();

  for (int k0 = 0; k0 < nk; ++k0) {
    const int cur = k0 & 1;
    if (k0 + 1 < nk) {
#pragma unroll
      for (int c = 0; c < 4; ++c) {
        gload_lds16(gA + (size_t)(c * 32) * K + (k0 + 1) * 64,
                    &smA[cur ^ 1][(c * 32 + wid * 8) * 64]);
        gload_lds16(gB + (size_t)(c * 32) * K + (k0 + 1) * 64,
                    &smB[cur ^ 1][(c * 32 + wid * 8) * 64]);
      }
    }
#pragma unroll
    for (int kk = 0; kk < 2; ++kk) {
      bf16x8 a[4], bb[4];
#pragma unroll
      for (int f = 0; f < 4; ++f) {
        a[f] = *(const bf16x8*)&smA[cur][(wm * 64 + f * 16 + li) * 64 + ((kk * 32 + lg * 8) ^ fswz)];
        bb[f] = *(const bf16x8*)&smB[cur][(wn * 64 + f * 16 + li) * 64 + ((kk * 32 + lg * 8) ^ fswz)];
      }
#pragma unroll
      for (int mf = 0; mf < 4; ++mf)
#pragma unroll
        for (int nf = 0; nf < 4; ++nf)
          acc[mf][nf] = __builtin_amdgcn_mfma_f32_16x16x32_bf16(a[mf], bb[nf], acc[mf][nf], 0, 0, 0);
    }
    __syncthreads();
  }

  // epilogue: C/D layout col = lane&15, row = (lane>>4)*4 + reg
#pragma unroll
  for (int mf = 0; mf < 4; ++mf) {
#pragma unroll
    for (int r2 = 0; r2 < 4; ++r2) {
      int mrow = m0 + wm * 64 + mf * 16 + lg * 4 + r2;
      size_t orow = (size_t)mrow;
      if (EPI == 2) {
        int w = mrow >> 6, t = mrow & 63;
        int bb2 = w >> 8, wi = (w >> 4) & 15, wj = w & 15;
        int i = t >> 3, j = t & 7;
        int p = (wi * 8 + i + 4) & 127, qq = (wj * 8 + j + 4) & 127;
        orow = (size_t)bb2 * 16384 + p * 128 + qq;
      }
#pragma unroll
      for (int nf = 0; nf < 4; ++nf) {
        int col = n0 + wn * 64 + nf * 16 + li;
        float v = acc[mf][nf][r2] + bias[col];
        if (EPI == 0) {
          Obf[(size_t)mrow * N + col] = f2bf(v);
        } else if (EPI == 1) {
          // tanh-GELU via sigmoid with fast rcp (bf16 output absorbs approx err)
          float y = 1.5957691f * (v + 0.044715f * v * v * v);
          float gl = v * __builtin_amdgcn_rcpf(1.f + __expf(-y));
          Obf[(size_t)mrow * N + col] = f2bf(gl);
        } else if (EPI == 2) {
          const float* rx = (const float*)resid;
          Obf[orow * 384 + col] = f2bf(v + rx[orow * 384 + col]);
        } else {
          const unsigned short* rx = (const unsigned short*)resid;
          Of[(size_t)mrow * N + col] = v + bf2f(rx[(size_t)mrow * N + col]);
        }
      }
    }
  }
}

// ---------------- windowed attention: one block per window, 4 waves x 3 heads ----------------
__global__ __launch_bounds__(256, 2)
void attn_kernel(const unsigned short* __restrict__ qkv, const float* __restrict__ btab,
                 const float* __restrict__ mask, unsigned short* __restrict__ out) {
  __shared__ unsigned short v_lds[4][64 * 40];  // V tile, row stride 40
  __shared__ unsigned short p_lds[4][64 * 72];  // P tile, row stride 72
  const int w = blockIdx.x;
  const int tid = threadIdx.x;
  const int wid = tid >> 6, lane = tid & 63;
  const int li = lane & 15, lg = lane >> 4;
  const float* mrow = mask + (size_t)(w & 255) * 4096;
  const size_t base = (size_t)w * 64;
  const float SC = 0.17677669529663688f;  // 32^-0.5

#pragma unroll 1
  for (int hi = 0; hi < 3; ++hi) {
    int h = wid * 3 + hi;
    bf16x8 aq[4], bk[4];
#pragma unroll
    for (int f = 0; f < 4; ++f) {
      size_t off = (base + f * 16 + li) * 1152 + h * 32 + lg * 8;
      aq[f] = *(const bf16x8*)&qkv[off];
      bk[f] = *(const bf16x8*)&qkv[off + 384];
    }
    f32x4 s[4][4] = {};
#pragma unroll
    for (int mf = 0; mf < 4; ++mf)
#pragma unroll
      for (int nf = 0; nf < 4; ++nf)
        s[mf][nf] = __builtin_amdgcn_mfma_f32_16x16x32_bf16(aq[mf], bk[nf], s[mf][nf], 0, 0, 0);

    {
      const unsigned short* vp = &qkv[(base + lane) * 1152 + 768 + h * 32];
      unsigned short* dp = &v_lds[wid][lane * 40];
#pragma unroll
      for (int c = 0; c < 4; ++c) *(bf16x8*)&dp[c * 8] = *(const bf16x8*)&vp[c * 8];
    }

#pragma unroll
    for (int mf = 0; mf < 4; ++mf) {
#pragma unroll
      for (int r = 0; r < 4; ++r) {
        int m = mf * 16 + lg * 4 + r;
        float mx = -1e30f;
#pragma unroll
        for (int nf = 0; nf < 4; ++nf) {
          int n = nf * 16 + li;
          int ridx = ((m >> 3) - (n >> 3) + 7) * 15 + (m & 7) - (n & 7) + 7;
          float val = s[mf][nf][r] * SC + btab[ridx * 12 + h] + mrow[m * 64 + n];
          s[mf][nf][r] = val;
          mx = fmaxf(mx, val);
        }
#pragma unroll
        for (int o2 = 1; o2 < 16; o2 <<= 1) mx = fmaxf(mx, __shfl_xor(mx, o2));
        float sum = 0.f;
#pragma unroll
        for (int nf = 0; nf < 4; ++nf) {
          float e = __expf(s[mf][nf][r] - mx);
          s[mf][nf][r] = e;
          sum += e;
        }
#pragma unroll
        for (int o2 = 1; o2 < 16; o2 <<= 1) sum += __shfl_xor(sum, o2);
        float inv = __builtin_amdgcn_rcpf(sum);
#pragma unroll
        for (int nf = 0; nf < 4; ++nf) s[mf][nf][r] *= inv;
      }
    }

#pragma unroll
    for (int mf = 0; mf < 4; ++mf)
#pragma unroll
      for (int nf = 0; nf < 4; ++nf)
#pragma unroll
        for (int r = 0; r < 4; ++r) {
          int m = mf * 16 + lg * 4 + r, n = nf * 16 + li;
          p_lds[wid][m * 72 + n] = f2bf(s[mf][nf][r]);
        }

    f32x4 o[4][2] = {};
#pragma unroll
    for (int kf = 0; kf < 2; ++kf) {
      bf16x8 bv[2];
#pragma unroll
      for (int df = 0; df < 2; ++df) {
        bf16x8 t;
#pragma unroll
        for (int e = 0; e < 8; ++e)
          t[e] = (short)v_lds[wid][(kf * 32 + lg * 8 + e) * 40 + df * 16 + li];
        bv[df] = t;
      }
#pragma unroll
      for (int mf = 0; mf < 4; ++mf) {
        bf16x8 pa = *(const bf16x8*)&p_lds[wid][(mf * 16 + li) * 72 + kf * 32 + lg * 8];
#pragma unroll
        for (int df = 0; df < 2; ++df)
          o[mf][df] = __builtin_amdgcn_mfma_f32_16x16x32_bf16(pa, bv[df], o[mf][df], 0, 0, 0);
      }
    }

#pragma unroll
    for (int mf = 0; mf < 4; ++mf)
#pragma unroll
      for (int df = 0; df < 2; ++df)
#pragma unroll
        for (int r = 0; r < 4; ++r) {
          size_t row = base + mf * 16 + lg * 4 + r;
          out[row * 384 + h * 32 + df * 16 + li] = f2bf(o[mf][df][r]);
        }
  }
}

extern "C" void kernel_launch(void* const* d_in, const int* in_sizes, int n_in,
                              void* d_out, int out_size, void* d_ws, size_t ws_size,
                              hipStream_t stream) {
  const float* x      = (const float*)d_in[0];
  const float* qkv_w  = (const float*)d_in[1];
  const float* qkv_b  = (const float*)d_in[2];
  const float* proj_w = (const float*)d_in[3];
  const float* proj_b = (const float*)d_in[4];
  const float* rel    = (const float*)d_in[5];
  const float* g1     = (const float*)d_in[6];
  const float* b1     = (const float*)d_in[7];
  const float* g2     = (const float*)d_in[8];
  const float* b2     = (const float*)d_in[9];
  const float* fc1_w  = (const float*)d_in[10];
  const float* fc1_b  = (const float*)d_in[11];
  const float* fc2_w  = (const float*)d_in[12];
  const float* fc2_b  = (const float*)d_in[13];
  const float* mask   = (const float*)d_in[14];
  float* out = (float*)d_out;
  char* ws = (char*)d_ws;

  const int M = 131072;  // B * H * W tokens
  unsigned short* hw     = (unsigned short*)ws;
  unsigned short* qkv    = (unsigned short*)(ws + 100663296);
  unsigned short* hmid   = (unsigned short*)ws;
  unsigned short* attn_o = (unsigned short*)(ws + 402653184);
  unsigned short* ln2o   = attn_o;
  unsigned short* x1b    = (unsigned short*)(ws + 503316480);
  unsigned short* wq     = (unsigned short*)(ws + 603979776);
  unsigned short* wp     = wq + 442368;
  unsigned short* w1     = wp + 147456;
  unsigned short* w2     = w1 + 589824;

  cvt_f32_bf16<<<(442368 + 255) / 256, 256, 0, stream>>>(qkv_w, wq, 442368);
  cvt_f32_bf16<<<(147456 + 255) / 256, 256, 0, stream>>>(proj_w, wp, 147456);
  cvt_f32_bf16<<<(589824 + 255) / 256, 256, 0, stream>>>(fc1_w, w1, 589824);
  cvt_f32_bf16<<<(589824 + 255) / 256, 256, 0, stream>>>(fc2_w, w2, 589824);

  // LN1 + shift + window partition
  ln_kernel<1><<<M / 4, 256, 0, stream>>>(x, g1, b1, hw);

  // QKV projection
  gemm_bt<0><<<9 * 1024, 256, 0, stream>>>(hw, wq, qkv_b, M, 1152, 384, 9, qkv, nullptr, nullptr);

  // windowed attention
  attn_kernel<<<2048, 256, 0, stream>>>(qkv, rel, mask, attn_o);

  // proj + window reverse + unshift + residual(x f32) -> x1 (bf16)
  gemm_bt<2><<<3 * 1024, 256, 0, stream>>>(attn_o, wp, proj_b, M, 384, 384, 3, x1b, x, nullptr);

  // LN2 (bf16 in)
  ln_bf16<<<M / 4, 256, 0, stream>>>(x1b, g2, b2, ln2o);

  // FC1 + GELU
  gemm_bt<1><<<12 * 1024, 256, 0, stream>>>(ln2o, w1, fc1_b, M, 1536, 384, 12, hmid, nullptr, nullptr);

  // FC2 + residual(x1 bf16) -> out (f32)
  gemm_bt<3><<<3 * 1024, 256, 0, stream>>>(hmid, w2, fc2_b, M, 384, 1536, 3, nullptr, x1b, out);
}

// Round 7
// 1145.186 us; speedup vs baseline: 1.3181x; 1.0284x over previous
//
#include <hip/hip_runtime.h>
#include <hip/hip_bf16.h>
#include <math.h>

typedef __attribute__((ext_vector_type(4))) float f32x4;
typedef __attribute__((ext_vector_type(8))) short bf16x8;

__device__ __forceinline__ unsigned short f2bf(float f) {
  unsigned int x = __builtin_bit_cast(unsigned int, f);
  x += 0x7fffu + ((x >> 16) & 1u);
  return (unsigned short)(x >> 16);
}
__device__ __forceinline__ float bf2f(unsigned short u) {
  unsigned int x = ((unsigned int)u) << 16;
  return __builtin_bit_cast(float, x);
}

__device__ __forceinline__ void gload_lds16(const void* g, void* l) {
  __builtin_amdgcn_global_load_lds(
      (const __attribute__((address_space(1))) unsigned int*)g,
      (__attribute__((address_space(3))) unsigned int*)l, 16, 0, 0);
}

// ---------------- f32 -> bf16 cast ----------------
__global__ void cvt_f32_bf16(const float* __restrict__ s, unsigned short* __restrict__ d, int n) {
  int i = blockIdx.x * 256 + threadIdx.x;
  if (i < n) d[i] = f2bf(s[i]);
}

// ---------------- LayerNorm, f32 input (optional shift+window gather) ----------------
template <int REMAP>
__global__ __launch_bounds__(256)
void ln_kernel(const float* __restrict__ x, const float* __restrict__ g,
               const float* __restrict__ b, unsigned short* __restrict__ dst_o) {
  int r = blockIdx.x * 4 + (threadIdx.x >> 6);
  int lane = threadIdx.x & 63;
  size_t src;
  if (REMAP) {
    int w = r >> 6, t = r & 63;
    int bb = w >> 8, wi = (w >> 4) & 15, wj = w & 15;
    int i = t >> 3, j = t & 7;
    int p = (wi * 8 + i + 4) & 127, q = (wj * 8 + j + 4) & 127;
    src = ((size_t)bb * 16384 + p * 128 + q) * 384;
  } else {
    src = (size_t)r * 384;
  }
  float v[6];
  float s = 0.f, s2 = 0.f;
#pragma unroll
  for (int m = 0; m < 6; ++m) {
    v[m] = x[src + lane + 64 * m];
    s += v[m];
    s2 += v[m] * v[m];
  }
#pragma unroll
  for (int o2 = 1; o2 < 64; o2 <<= 1) {
    s += __shfl_xor(s, o2);
    s2 += __shfl_xor(s2, o2);
  }
  float mu = s * (1.f / 384.f);
  float var = s2 * (1.f / 384.f) - mu * mu;
  float ri = rsqrtf(var + 1e-5f);
  size_t dst = (size_t)r * 384;
#pragma unroll
  for (int m = 0; m < 6; ++m) {
    int c = lane + 64 * m;
    dst_o[dst + c] = f2bf((v[m] - mu) * ri * g[c] + b[c]);
  }
}

// ---------------- LayerNorm, bf16 input (for LN2 on bf16 x1) ----------------
__global__ __launch_bounds__(256)
void ln_bf16(const unsigned short* __restrict__ x, const float* __restrict__ g,
             const float* __restrict__ b, unsigned short* __restrict__ dst_o) {
  int r = blockIdx.x * 4 + (threadIdx.x >> 6);
  int lane = threadIdx.x & 63;
  size_t src = (size_t)r * 384;
  float v[6];
  float s = 0.f, s2 = 0.f;
#pragma unroll
  for (int m = 0; m < 3; ++m) {
    unsigned int u = *(const unsigned int*)&x[src + lane * 2 + 128 * m];
    v[2 * m] = bf2f((unsigned short)(u & 0xffffu));
    v[2 * m + 1] = bf2f((unsigned short)(u >> 16));
    s += v[2 * m] + v[2 * m + 1];
    s2 += v[2 * m] * v[2 * m] + v[2 * m + 1] * v[2 * m + 1];
  }
#pragma unroll
  for (int o2 = 1; o2 < 64; o2 <<= 1) {
    s += __shfl_xor(s, o2);
    s2 += __shfl_xor(s2, o2);
  }
  float mu = s * (1.f / 384.f);
  float var = s2 * (1.f / 384.f) - mu * mu;
  float ri = rsqrtf(var + 1e-5f);
#pragma unroll
  for (int m = 0; m < 3; ++m) {
    int c = lane * 2 + 128 * m;
    unsigned int lo = f2bf((v[2 * m] - mu) * ri * g[c] + b[c]);
    unsigned int hi = f2bf((v[2 * m + 1] - mu) * ri * g[c + 1] + b[c + 1]);
    *(unsigned int*)&dst_o[src + c] = lo | (hi << 16);
  }
}

// ---------------- GEMM (T3+T4+T5): C(M,N) = A(M,K) * B(N,K)^T ----------------
// 512 threads / 8 waves (4M x 2N, wave tile 64x64). Block tile 256x128, BK=64.
// TRI-buffered LDS (3 x 48KB, dynamic). Counted-vmcnt pipeline: per K-tile t,
//   s_waitcnt vmcnt(6)   // tile t's 6 loads/wave landed; tile t+1's 6 in flight
//   s_barrier            // all waves: tile t ready AND compute(t-1) done
//   issue stage(t+2)     // into buffer (t+2)%3 (safe: last read at iter t-1)
//   2x { 8 ds_read (swizzled), setprio(1), 16 MFMA, setprio(0) }
// Never vmcnt(0) in main loop (T4); last iteration peeled with vmcnt(0).
// T2 both-sides XOR swizzle (0 conflicts, verified R4). m204 XCD swizzle.
// EPI 0: out = bf16(acc + bias)                         -> Obf
// EPI 1: out = bf16(gelu_tanh(acc + bias))              -> Obf  (rcpf sigmoid)
// EPI 2: proj: scatter window->image, bf16(v + x_f32)   -> Obf (x1 bf16)
// EPI 3: out = acc + bias + bf16resid                   -> Of (f32)
template <int EPI>
__global__ __launch_bounds__(512, 1)
void gemm8(const unsigned short* __restrict__ A, const unsigned short* __restrict__ Bw,
           const float* __restrict__ bias, int M, int N, int K, int NT,
           unsigned short* __restrict__ Obf, const void* __restrict__ resid,
           float* __restrict__ Of) {
  extern __shared__ unsigned short lds[];  // 3 buffers x (A 16384 + B 8192) ushorts
  const int tid = threadIdx.x;
  const int lane = tid & 63;
  const int wid = tid >> 6;               // 0..7
  const int wm = wid >> 1, wn = wid & 1;  // wave grid 4M x 2N
  const int li = lane & 15, lg = lane >> 4;

  // bijective XCD swizzle (m204)
  const int nwg = gridDim.x;
  const int orig = blockIdx.x;
  const int q = nwg >> 3, r = nwg & 7;
  const int xcd = orig & 7, loc = orig >> 3;
  const int wg = (xcd < r ? xcd * (q + 1) : r * (q + 1) + (xcd - r) * q) + loc;
  const int m0 = (wg / NT) * 256;
  const int n0 = (wg % NT) * 128;

  // staging: per load-round 512 threads x 16B = 64 rows x 128B. Linear LDS
  // dest (gload: wave base + lane*16); inverse-swizzled global source col.
  const int srow = wid * 8 + (lane >> 3);           // row within round, 0..63
  const int scol = ((lane & 7) ^ (lane >> 3)) * 8;  // pre-swizzled col
  const unsigned short* gA = A + (size_t)(m0 + srow) * K + scol;
  const unsigned short* gB = Bw + (size_t)(n0 + srow) * K + scol;

  const int nk = K >> 6;
  const int fswz = (li & 7) << 3;  // fragment read swizzle (frag row&7 == li&7)
  f32x4 acc[4][4] = {};

  // stage K-tile k into buffer b: A 4 rounds (256 rows), B 2 rounds (128 rows)
  auto stage = [&](int k, int b) {
    unsigned short* dA = lds + b * 24576;
    unsigned short* dB = dA + 16384;
#pragma unroll
    for (int c = 0; c < 4; ++c)
      gload_lds16(gA + (size_t)(c * 64) * K + k * 64, &dA[c * 4096 + wid * 512]);
#pragma unroll
    for (int c = 0; c < 2; ++c)
      gload_lds16(gB + (size_t)(c * 64) * K + k * 64, &dB[c * 4096 + wid * 512]);
  };

  // prologue: 2 tiles in flight
  stage(0, 0);
  stage(1, 1);

  int cur = 0;
  for (int t = 0; t < nk; ++t) {
    if (t < nk - 1) {
      asm volatile("s_waitcnt vmcnt(6)" ::: "memory");
    } else {
      asm volatile("s_waitcnt vmcnt(0)" ::: "memory");
    }
    __builtin_amdgcn_s_barrier();
    __builtin_amdgcn_sched_barrier(0);
    if (t + 2 < nk) {
      int nb = cur + 2;
      if (nb >= 3) nb -= 3;
      stage(t + 2, nb);
    }
    const unsigned short* pA = lds + cur * 24576;
    const unsigned short* pB = pA + 16384;
#pragma unroll
    for (int kk = 0; kk < 2; ++kk) {
      bf16x8 a[4], bb[4];
#pragma unroll
      for (int f = 0; f < 4; ++f) {
        a[f] = *(const bf16x8*)&pA[(wm * 64 + f * 16 + li) * 64 + ((kk * 32 + lg * 8) ^ fswz)];
        bb[f] = *(const bf16x8*)&pB[(wn * 64 + f * 16 + li) * 64 + ((kk * 32 + lg * 8) ^ fswz)];
      }
      __builtin_amdgcn_s_setprio(1);
#pragma unroll
      for (int mf = 0; mf < 4; ++mf)
#pragma unroll
        for (int nf = 0; nf < 4; ++nf)
          acc[mf][nf] = __builtin_amdgcn_mfma_f32_16x16x32_bf16(a[mf], bb[nf], acc[mf][nf], 0, 0, 0);
      __builtin_amdgcn_s_setprio(0);
    }
    ++cur;
    if (cur == 3) cur = 0;
  }

  // epilogue: C/D layout col = lane&15, row = (lane>>4)*4 + reg
#pragma unroll
  for (int mf = 0; mf < 4; ++mf) {
#pragma unroll
    for (int r2 = 0; r2 < 4; ++r2) {
      int mrow = m0 + wm * 64 + mf * 16 + lg * 4 + r2;
      size_t orow = (size_t)mrow;
      if (EPI == 2) {
        int w = mrow >> 6, t = mrow & 63;
        int bb2 = w >> 8, wi = (w >> 4) & 15, wj = w & 15;
        int i = t >> 3, j = t & 7;
        int p = (wi * 8 + i + 4) & 127, qq = (wj * 8 + j + 4) & 127;
        orow = (size_t)bb2 * 16384 + p * 128 + qq;
      }
#pragma unroll
      for (int nf = 0; nf < 4; ++nf) {
        int col = n0 + wn * 64 + nf * 16 + li;
        float v = acc[mf][nf][r2] + bias[col];
        if (EPI == 0) {
          Obf[(size_t)mrow * N + col] = f2bf(v);
        } else if (EPI == 1) {
          float y = 1.5957691f * (v + 0.044715f * v * v * v);
          float gl = v * __builtin_amdgcn_rcpf(1.f + __expf(-y));
          Obf[(size_t)mrow * N + col] = f2bf(gl);
        } else if (EPI == 2) {
          const float* rx = (const float*)resid;
          Obf[orow * 384 + col] = f2bf(v + rx[orow * 384 + col]);
        } else {
          const unsigned short* rx = (const unsigned short*)resid;
          Of[(size_t)mrow * N + col] = v + bf2f(rx[(size_t)mrow * N + col]);
        }
      }
    }
  }
}

// ---------------- windowed attention: one block per window, 4 waves x 3 heads ----------------
__global__ __launch_bounds__(256, 2)
void attn_kernel(const unsigned short* __restrict__ qkv, const float* __restrict__ btab,
                 const float* __restrict__ mask, unsigned short* __restrict__ out) {
  __shared__ unsigned short v_lds[4][64 * 40];  // V tile, row stride 40
  __shared__ unsigned short p_lds[4][64 * 72];  // P tile, row stride 72
  const int w = blockIdx.x;
  const int tid = threadIdx.x;
  const int wid = tid >> 6, lane = tid & 63;
  const int li = lane & 15, lg = lane >> 4;
  const float* mrow = mask + (size_t)(w & 255) * 4096;
  const size_t base = (size_t)w * 64;
  const float SC = 0.17677669529663688f;  // 32^-0.5

#pragma unroll 1
  for (int hi = 0; hi < 3; ++hi) {
    int h = wid * 3 + hi;
    bf16x8 aq[4], bk[4];
#pragma unroll
    for (int f = 0; f < 4; ++f) {
      size_t off = (base + f * 16 + li) * 1152 + h * 32 + lg * 8;
      aq[f] = *(const bf16x8*)&qkv[off];
      bk[f] = *(const bf16x8*)&qkv[off + 384];
    }
    f32x4 s[4][4] = {};
#pragma unroll
    for (int mf = 0; mf < 4; ++mf)
#pragma unroll
      for (int nf = 0; nf < 4; ++nf)
        s[mf][nf] = __builtin_amdgcn_mfma_f32_16x16x32_bf16(aq[mf], bk[nf], s[mf][nf], 0, 0, 0);

    {
      const unsigned short* vp = &qkv[(base + lane) * 1152 + 768 + h * 32];
      unsigned short* dp = &v_lds[wid][lane * 40];
#pragma unroll
      for (int c = 0; c < 4; ++c) *(bf16x8*)&dp[c * 8] = *(const bf16x8*)&vp[c * 8];
    }

#pragma unroll
    for (int mf = 0; mf < 4; ++mf) {
#pragma unroll
      for (int r = 0; r < 4; ++r) {
        int m = mf * 16 + lg * 4 + r;
        float mx = -1e30f;
#pragma unroll
        for (int nf = 0; nf < 4; ++nf) {
          int n = nf * 16 + li;
          int ridx = ((m >> 3) - (n >> 3) + 7) * 15 + (m & 7) - (n & 7) + 7;
          float val = s[mf][nf][r] * SC + btab[ridx * 12 + h] + mrow[m * 64 + n];
          s[mf][nf][r] = val;
          mx = fmaxf(mx, val);
        }
#pragma unroll
        for (int o2 = 1; o2 < 16; o2 <<= 1) mx = fmaxf(mx, __shfl_xor(mx, o2));
        float sum = 0.f;
#pragma unroll
        for (int nf = 0; nf < 4; ++nf) {
          float e = __expf(s[mf][nf][r] - mx);
          s[mf][nf][r] = e;
          sum += e;
        }
#pragma unroll
        for (int o2 = 1; o2 < 16; o2 <<= 1) sum += __shfl_xor(sum, o2);
        float inv = __builtin_amdgcn_rcpf(sum);
#pragma unroll
        for (int nf = 0; nf < 4; ++nf) s[mf][nf][r] *= inv;
      }
    }

#pragma unroll
    for (int mf = 0; mf < 4; ++mf)
#pragma unroll
      for (int nf = 0; nf < 4; ++nf)
#pragma unroll
        for (int r = 0; r < 4; ++r) {
          int m = mf * 16 + lg * 4 + r, n = nf * 16 + li;
          p_lds[wid][m * 72 + n] = f2bf(s[mf][nf][r]);
        }

    f32x4 o[4][2] = {};
#pragma unroll
    for (int kf = 0; kf < 2; ++kf) {
      bf16x8 bv[2];
#pragma unroll
      for (int df = 0; df < 2; ++df) {
        bf16x8 t;
#pragma unroll
        for (int e = 0; e < 8; ++e)
          t[e] = (short)v_lds[wid][(kf * 32 + lg * 8 + e) * 40 + df * 16 + li];
        bv[df] = t;
      }
#pragma unroll
      for (int mf = 0; mf < 4; ++mf) {
        bf16x8 pa = *(const bf16x8*)&p_lds[wid][(mf * 16 + li) * 72 + kf * 32 + lg * 8];
#pragma unroll
        for (int df = 0; df < 2; ++df)
          o[mf][df] = __builtin_amdgcn_mfma_f32_16x16x32_bf16(pa, bv[df], o[mf][df], 0, 0, 0);
      }
    }

#pragma unroll
    for (int mf = 0; mf < 4; ++mf)
#pragma unroll
      for (int df = 0; df < 2; ++df)
#pragma unroll
        for (int r = 0; r < 4; ++r) {
          size_t row = base + mf * 16 + lg * 4 + r;
          out[row * 384 + h * 32 + df * 16 + li] = f2bf(o[mf][df][r]);
        }
  }
}

extern "C" void kernel_launch(void* const* d_in, const int* in_sizes, int n_in,
                              void* d_out, int out_size, void* d_ws, size_t ws_size,
                              hipStream_t stream) {
  const float* x      = (const float*)d_in[0];
  const float* qkv_w  = (const float*)d_in[1];
  const float* qkv_b  = (const float*)d_in[2];
  const float* proj_w = (const float*)d_in[3];
  const float* proj_b = (const float*)d_in[4];
  const float* rel    = (const float*)d_in[5];
  const float* g1     = (const float*)d_in[6];
  const float* b1     = (const float*)d_in[7];
  const float* g2     = (const float*)d_in[8];
  const float* b2     = (const float*)d_in[9];
  const float* fc1_w  = (const float*)d_in[10];
  const float* fc1_b  = (const float*)d_in[11];
  const float* fc2_w  = (const float*)d_in[12];
  const float* fc2_b  = (const float*)d_in[13];
  const float* mask   = (const float*)d_in[14];
  float* out = (float*)d_out;
  char* ws = (char*)d_ws;

  const int M = 131072;  // B * H * W tokens
  const int LDS_BYTES = 3 * 49152;  // tri-buffered 144 KB
  (void)hipFuncSetAttribute((const void*)gemm8<0>, hipFuncAttributeMaxDynamicSharedMemorySize, LDS_BYTES);
  (void)hipFuncSetAttribute((const void*)gemm8<1>, hipFuncAttributeMaxDynamicSharedMemorySize, LDS_BYTES);
  (void)hipFuncSetAttribute((const void*)gemm8<2>, hipFuncAttributeMaxDynamicSharedMemorySize, LDS_BYTES);
  (void)hipFuncSetAttribute((const void*)gemm8<3>, hipFuncAttributeMaxDynamicSharedMemorySize, LDS_BYTES);

  unsigned short* hw     = (unsigned short*)ws;
  unsigned short* qkv    = (unsigned short*)(ws + 100663296);
  unsigned short* hmid   = (unsigned short*)ws;
  unsigned short* attn_o = (unsigned short*)(ws + 402653184);
  unsigned short* ln2o   = attn_o;
  unsigned short* x1b    = (unsigned short*)(ws + 503316480);
  unsigned short* wq     = (unsigned short*)(ws + 603979776);
  unsigned short* wp     = wq + 442368;
  unsigned short* w1     = wp + 147456;
  unsigned short* w2     = w1 + 589824;

  cvt_f32_bf16<<<(442368 + 255) / 256, 256, 0, stream>>>(qkv_w, wq, 442368);
  cvt_f32_bf16<<<(147456 + 255) / 256, 256, 0, stream>>>(proj_w, wp, 147456);
  cvt_f32_bf16<<<(589824 + 255) / 256, 256, 0, stream>>>(fc1_w, w1, 589824);
  cvt_f32_bf16<<<(589824 + 255) / 256, 256, 0, stream>>>(fc2_w, w2, 589824);

  // LN1 + shift + window partition
  ln_kernel<1><<<M / 4, 256, 0, stream>>>(x, g1, b1, hw);

  // QKV projection: grid (M/256)*(N/128)
  gemm8<0><<<512 * 9, 512, LDS_BYTES, stream>>>(hw, wq, qkv_b, M, 1152, 384, 9, qkv, nullptr, nullptr);

  // windowed attention
  attn_kernel<<<2048, 256, 0, stream>>>(qkv, rel, mask, attn_o);

  // proj + window reverse + unshift + residual(x f32) -> x1 (bf16)
  gemm8<2><<<512 * 3, 512, LDS_BYTES, stream>>>(attn_o, wp, proj_b, M, 384, 384, 3, x1b, x, nullptr);

  // LN2 (bf16 in)
  ln_bf16<<<M / 4, 256, 0, stream>>>(x1b, g2, b2, ln2o);

  // FC1 + GELU
  gemm8<1><<<512 * 12, 512, LDS_BYTES, stream>>>(ln2o, w1, fc1_b, M, 1536, 384, 12, hmid, nullptr, nullptr);

  // FC2 + residual(x1 bf16) -> out (f32)
  gemm8<3><<<512 * 3, 512, LDS_BYTES, stream>>>(hmid, w2, fc2_b, M, 384, 1536, 3, nullptr, x1b, out);
}